// Round 4
// baseline (994.096 us; speedup 1.0000x reference)
//
#include <hip/hip_runtime.h>
#include <hip/hip_bf16.h>
#include <stdint.h>

// XCA (cross-covariance attention), B=8 N=8192 C=384 H=8 Dh=48.
// R7 == R6 resubmit (R6 bench was an infra failure, "container failed twice";
// kernel never executed). Theory unchanged:
// R5's 650us k_gemm_qkv was REGISTER SPILLING: __launch_bounds__(256,4)
// forced VGPR=64 but the body needs ~96 live regs (acc 64 + frags 32) ->
// scratch traffic = 2.47 GB/dispatch (FETCH 1.1GB + WRITE 1.3GB).
// Fix: drop the launch bounds on the 4x4-acc GEMM kernels (natural VGPR ~120
// -> 4 waves/SIMD per m69, no spills) and on k_weff (~140 regs needed).
// Keep: k_cvt f32->bf16 pass, gload_lds staging, swapped-operand q/k stores.

typedef __bf16 bf16_t;
typedef __attribute__((ext_vector_type(8))) __bf16 bf16x8;
typedef __attribute__((ext_vector_type(4))) __bf16 bf16x4;
typedef __attribute__((ext_vector_type(4))) float f32x4;

#define NTOK 8192
#define CDIM 384
#define WH   25165824   // 8*8*48*8192 elements per q/k plane
#define DHN  393216     // 48*8192

#define XCHUNKS 3145728   // 25,165,824 X elems / 8
#define TCHUNKS 3201024   // + 442,368 W elems / 8

__device__ __forceinline__ f32x4 mfma16(bf16x8 a, bf16x8 b, f32x4 c) {
  return __builtin_amdgcn_mfma_f32_16x16x32_bf16(a, b, c, 0, 0, 0);
}

// async global->LDS, 16B per lane (wave-uniform base + lane*16 idiom).
__device__ __forceinline__ void gload16(bf16_t* lds, const bf16_t* g) {
  __builtin_amdgcn_global_load_lds(
      (const __attribute__((address_space(1))) void*)g,
      (__attribute__((address_space(3))) void*)lds, 16, 0, 0);
}

template <bool BF16>
__device__ __forceinline__ bf16x8 load8(const void* p, int idx) {
  if constexpr (BF16) {
    return *(const bf16x8*)((const bf16_t*)p + idx);
  } else {
    const float* f = (const float*)p + idx;
    f32x4 a = *(const f32x4*)f;
    f32x4 b = *(const f32x4*)(f + 4);
    bf16x8 r;
    r[0] = (bf16_t)a[0]; r[1] = (bf16_t)a[1]; r[2] = (bf16_t)a[2]; r[3] = (bf16_t)a[3];
    r[4] = (bf16_t)b[0]; r[5] = (bf16_t)b[1]; r[6] = (bf16_t)b[2]; r[7] = (bf16_t)b[3];
    return r;
  }
}

// ---------------- probe: are inputs bf16 (1) or f32 (0)? ----------------
__global__ void k_probe(const uint32_t* __restrict__ X, int* __restrict__ flag) {
  __shared__ int cnt;
  if (threadIdx.x == 0) cnt = 0;
  __syncthreads();
  const uint32_t w = X[threadIdx.x];
  const int e = (int)((w >> 7) & 0xFF);  // exponent of low-16 as bf16
  const int sane = (e >= 110 && e <= 131) ? 1 : 0;
  atomicAdd(&cnt, sane);
  __syncthreads();
  if (threadIdx.x == 0) *flag = (cnt >= 128) ? 1 : 0;
}

// ---------------- zero fp32 accumulators ----------------
__global__ void k_zero(float* __restrict__ p, int n) {
  int i = blockIdx.x * 256 + threadIdx.x;
  if (i < n) p[i] = 0.f;
}

// ---------------- cvt: X,Wqkv (f32 or bf16) -> bf16 workspace ----------------
__global__ void k_cvt(const void* __restrict__ X, const void* __restrict__ Wqkv,
                      bf16_t* __restrict__ Xb, bf16_t* __restrict__ Wb,
                      const int* __restrict__ flagp) {
  const int isb = *flagp;
  const int G = gridDim.x * 256;
  for (int c = blockIdx.x * 256 + threadIdx.x; c < TCHUNKS; c += G) {
    const bool isX = c < XCHUNKS;
    const int lc = isX ? c : c - XCHUNKS;          // chunk within its buffer
    const void* src = isX ? X : Wqkv;
    bf16_t* dst = (isX ? Xb : Wb) + (size_t)lc * 8;
    if (isb) {
      *(bf16x8*)dst = *((const bf16x8*)src + lc);
    } else {
      const f32x4 a = *((const f32x4*)src + lc * 2);
      const f32x4 b = *((const f32x4*)src + lc * 2 + 1);
      bf16x8 r;
      r[0] = (bf16_t)a[0]; r[1] = (bf16_t)a[1]; r[2] = (bf16_t)a[2]; r[3] = (bf16_t)a[3];
      r[4] = (bf16_t)b[0]; r[5] = (bf16_t)b[1]; r[6] = (bf16_t)b[2]; r[7] = (bf16_t)b[3];
      *(bf16x8*)dst = r;
    }
  }
}

// ---------------- K1: qkv = x @ w_qkv^T ----------------
// Grid (512 m-tiles, 3). blockIdx.y = which (0=q,1=k,2=v); 3 jt per block.
// q/k tiles use swapped MFMA (D row = token) -> bf16x4 stores along N.
// v tiles use original order (D row = channel) -> bf16x4 stores along C.
template <bool BF16>
__device__ __forceinline__ void qkv_body(const void* __restrict__ X,
                                         const void* __restrict__ Wqkv,
                                         bf16_t* __restrict__ qkv,
                                         bf16_t* As, bf16_t* Bs) {
  const int tid = threadIdx.x;
  const int lane = tid & 63;
  const int wr = tid >> 7, wc = (tid >> 6) & 1;
  const int q4 = lane >> 4, l16 = lane & 15;
  const int which = blockIdx.y;
  const int rowB0 = blockIdx.x * 128;
  const int r0 = tid >> 2, kk = (tid & 3) << 3;
  const int bb = rowB0 >> 13;       // batch index (tiles never cross b)
  const int nB = rowB0 & 8191;      // token base within batch

  const bf16_t* XB = (const bf16_t*)X;
  const bf16_t* WB = (const bf16_t*)Wqkv;

  for (int jtt = 0; jtt < 3; jtt++) {
    const int rowA0 = (which * 3 + jtt) * 128;
    f32x4 acc[4][4];
#pragma unroll
    for (int i = 0; i < 4; i++)
#pragma unroll
      for (int j = 0; j < 4; j++) acc[i][j] = (f32x4){0.f, 0.f, 0.f, 0.f};

    for (int k0 = 0; k0 < CDIM; k0 += 32) {
      if constexpr (BF16) {
        __syncthreads();  // prior iteration's LDS frag reads complete
        gload16(As + tid * 8,         WB + (rowA0 + r0) * CDIM + k0 + kk);
        gload16(As + (tid + 256) * 8, WB + (rowA0 + r0 + 64) * CDIM + k0 + kk);
        gload16(Bs + tid * 8,         XB + (rowB0 + r0) * CDIM + k0 + kk);
        gload16(Bs + (tid + 256) * 8, XB + (rowB0 + r0 + 64) * CDIM + k0 + kk);
        __syncthreads();  // syncthreads drains vmcnt -> staging complete
      } else {
        bf16x8 a0 = load8<false>(Wqkv, (rowA0 + r0) * CDIM + k0 + kk);
        bf16x8 a1 = load8<false>(Wqkv, (rowA0 + r0 + 64) * CDIM + k0 + kk);
        bf16x8 b0 = load8<false>(X, (rowB0 + r0) * CDIM + k0 + kk);
        bf16x8 b1 = load8<false>(X, (rowB0 + r0 + 64) * CDIM + k0 + kk);
        __syncthreads();
        *(bf16x8*)&As[tid * 8] = a0;
        *(bf16x8*)&As[(tid + 256) * 8] = a1;
        *(bf16x8*)&Bs[tid * 8] = b0;
        *(bf16x8*)&Bs[(tid + 256) * 8] = b1;
        __syncthreads();
      }
      bf16x8 af[4], bfr[4];
#pragma unroll
      for (int i = 0; i < 4; i++) {
        af[i]  = *(const bf16x8*)&As[(wr * 64 + i * 16 + l16) * 32 + q4 * 8];
        bfr[i] = *(const bf16x8*)&Bs[(wc * 64 + i * 16 + l16) * 32 + q4 * 8];
      }
      if (which < 2) {
#pragma unroll
        for (int i = 0; i < 4; i++)
#pragma unroll
          for (int j = 0; j < 4; j++) acc[i][j] = mfma16(bfr[j], af[i], acc[i][j]);
      } else {
#pragma unroll
        for (int i = 0; i < 4; i++)
#pragma unroll
          for (int j = 0; j < 4; j++) acc[i][j] = mfma16(af[i], bfr[j], acc[i][j]);
      }
    }

    if (which < 2) {
      // swapped: acc[i][j][r] = D[token = rowB0+wc*64+j*16+q4*4+r][ch = rowA0+wr*64+i*16+l16]
#pragma unroll
      for (int i = 0; i < 4; i++) {
        const int rin = jtt * 128 + wr * 64 + i * 16 + l16;  // channel within plane
        const int h = rin / 48, dh = rin - h * 48;
        bf16_t* rowp = qkv + which * WH + (bb * 8 + h) * DHN + dh * NTOK
                       + nB + wc * 64 + q4 * 4;
#pragma unroll
        for (int j = 0; j < 4; j++) {
          bf16x4 o = {(bf16_t)acc[i][j][0], (bf16_t)acc[i][j][1],
                      (bf16_t)acc[i][j][2], (bf16_t)acc[i][j][3]};
          *(bf16x4*)(rowp + j * 16) = o;
        }
      }
    } else {
      // original: acc[i][j][r] = D[ch = rowA0+wr*64+i*16+q4*4+r][token = rowB0+wc*64+j*16+l16]
#pragma unroll
      for (int i = 0; i < 4; i++) {
        const int rin0 = jtt * 128 + wr * 64 + i * 16 + q4 * 4;  // c within v
#pragma unroll
        for (int j = 0; j < 4; j++) {
          const int mg = rowB0 + wc * 64 + j * 16 + l16;
          bf16x4 o = {(bf16_t)acc[i][j][0], (bf16_t)acc[i][j][1],
                      (bf16_t)acc[i][j][2], (bf16_t)acc[i][j][3]};
          *(bf16x4*)(qkv + 2 * WH + mg * CDIM + rin0) = o;
        }
      }
    }
  }
}

// main path: inputs already bf16 in workspace, no flag.
// NO __launch_bounds__: body needs ~96+ live VGPRs; capping causes scratch
// spills (R5: VGPR=64 -> 2.47 GB/dispatch spill traffic, 650us). Natural
// allocation ~120 VGPR -> 4 waves/SIMD (m69) without spills.
__global__ void k_gemm_qkv(
    const bf16_t* __restrict__ Xb, const bf16_t* __restrict__ Wb,
    bf16_t* __restrict__ qkv) {
  __shared__ __align__(16) bf16_t As[128 * 32];
  __shared__ __align__(16) bf16_t Bs[128 * 32];
  qkv_body<true>(Xb, Wb, qkv, As, Bs);
}

// fallback path (ws too small for cvt buffers): flag-gated pair on raw inputs.
__global__ void k_gemm_qkv_bf16(
    const void* __restrict__ X, const void* __restrict__ Wqkv,
    bf16_t* __restrict__ qkv, const int* __restrict__ flagp) {
  __shared__ __align__(16) bf16_t As[128 * 32];
  __shared__ __align__(16) bf16_t Bs[128 * 32];
  if (!*flagp) return;
  qkv_body<true>(X, Wqkv, qkv, As, Bs);
}

__global__ void k_gemm_qkv_f32(
    const void* __restrict__ X, const void* __restrict__ Wqkv,
    bf16_t* __restrict__ qkv, const int* __restrict__ flagp) {
  __shared__ __align__(16) bf16_t As[128 * 32];
  __shared__ __align__(16) bf16_t Bs[128 * 32];
  if (*flagp) return;
  qkv_body<false>(X, Wqkv, qkv, As, Bs);
}

// ---------------- K2: Gram S=Q K^T + sumsq ----------------
__global__ __launch_bounds__(256, 2) void k_gram(
    const bf16_t* __restrict__ qkv, float* __restrict__ S_acc, float* __restrict__ ssq_acc) {
  __shared__ __align__(16) float sm[9312];  // 37,248 B
  bf16_t* Qs = (bf16_t*)sm;                 // 6144 bf16 = [4][48][32]
  bf16_t* Ks = Qs + 6144;
  float* ssq_sm = sm + 9216;                // 96 floats

  const int tid = threadIdx.x;
  const int wave = tid >> 6, lane = tid & 63, q4 = lane >> 4, l16 = lane & 15;
  const int s = blockIdx.x, bh = blockIdx.y;
  const bf16_t* Qg = qkv + bh * DHN;
  const bf16_t* Kg = qkv + WH + bh * DHN;

  if (tid < 96) ssq_sm[tid] = 0.f;

  f32x4 acc[3][3];
#pragma unroll
  for (int i = 0; i < 3; i++)
#pragma unroll
    for (int j = 0; j < 3; j++) acc[i][j] = (f32x4){0.f, 0.f, 0.f, 0.f};
  float qss[3] = {0.f, 0.f, 0.f}, kss[3] = {0.f, 0.f, 0.f};

  for (int t0 = 0; t0 < 8; t0++) {
    const int n0 = s * 1024 + t0 * 128;
    bf16x8 qv[3], kv[3];
#pragma unroll
    for (int jj = 0; jj < 3; jj++) {
      const int c = jj * 256 + tid;
      const int st = c / 192, rem = c - st * 192;
      const int row = rem >> 2, kk = (rem & 3) << 3;
      const int gofs = row * NTOK + n0 + st * 32 + kk;
      qv[jj] = *(const bf16x8*)(Qg + gofs);
      kv[jj] = *(const bf16x8*)(Kg + gofs);
    }
    __syncthreads();
#pragma unroll
    for (int jj = 0; jj < 3; jj++) {
      *(bf16x8*)&Qs[(jj * 256 + tid) * 8] = qv[jj];
      *(bf16x8*)&Ks[(jj * 256 + tid) * 8] = kv[jj];
    }
    __syncthreads();
    bf16x8 qf[3], kf[3];
#pragma unroll
    for (int i = 0; i < 3; i++) {
      qf[i] = *(const bf16x8*)&Qs[wave * 1536 + (i * 16 + l16) * 32 + q4 * 8];
      kf[i] = *(const bf16x8*)&Ks[wave * 1536 + (i * 16 + l16) * 32 + q4 * 8];
    }
#pragma unroll
    for (int i = 0; i < 3; i++) {
#pragma unroll
      for (int u = 0; u < 8; u++) {
        const float qv2 = (float)qf[i][u], kv2 = (float)kf[i][u];
        qss[i] += qv2 * qv2;
        kss[i] += kv2 * kv2;
      }
#pragma unroll
      for (int j = 0; j < 3; j++) acc[i][j] = mfma16(qf[i], kf[j], acc[i][j]);
    }
  }

  __syncthreads();
  float* red = sm;  // 4 waves x 2304 fp32
#pragma unroll
  for (int i = 0; i < 3; i++)
#pragma unroll
    for (int j = 0; j < 3; j++)
#pragma unroll
      for (int r = 0; r < 4; r++)
        red[wave * 2304 + (i * 3 + j) * 256 + lane * 4 + r] = acc[i][j][r];
#pragma unroll
  for (int i = 0; i < 3; i++) {
    atomicAdd(&ssq_sm[i * 16 + l16], qss[i]);
    atomicAdd(&ssq_sm[48 + i * 16 + l16], kss[i]);
  }
  __syncthreads();
  for (int idx = tid; idx < 2304; idx += 256) {
    const float v = red[idx] + red[2304 + idx] + red[4608 + idx] + red[6912 + idx];
    const int tile = idx >> 8, ln = (idx >> 2) & 63, r = idx & 3;
    const int i = tile / 3, j = tile - i * 3;
    const int d = i * 16 + ((ln >> 4) << 2) + r;
    const int e = j * 16 + (ln & 15);
    atomicAdd(&S_acc[bh * 2304 + d * 48 + e], v);
  }
  if (tid < 96) atomicAdd(&ssq_acc[bh * 96 + tid], ssq_sm[tid]);
}

// ---------------- K3: softmax(S / (|q_d||k_e|)) ----------------
__global__ void k_softmax(const float* __restrict__ S_acc, const float* __restrict__ ssq_acc,
                          float* __restrict__ attn_f) {
  __shared__ float invk_sm[48];
  const int bh = blockIdx.x, d = threadIdx.x;
  if (d < 48) invk_sm[d] = 1.f / fmaxf(sqrtf(ssq_acc[bh * 96 + 48 + d]), 1e-12f);
  __syncthreads();
  if (d < 48) {
    const float invq = 1.f / fmaxf(sqrtf(ssq_acc[bh * 96 + d]), 1e-12f);
    float lg[48], mx = -1e30f;
#pragma unroll
    for (int e = 0; e < 48; e++) {
      lg[e] = S_acc[bh * 2304 + d * 48 + e] * invq * invk_sm[e];
      mx = fmaxf(mx, lg[e]);
    }
    float ssum = 0.f;
#pragma unroll
    for (int e = 0; e < 48; e++) { lg[e] = expf(lg[e] - mx); ssum += lg[e]; }
    const float inv = 1.f / ssum;
#pragma unroll
    for (int e = 0; e < 48; e++) attn_f[bh * 2304 + d * 48 + e] = lg[e] * inv;
  }
}

// ---------------- K4: Weff_b[c'][h*48+e] = sum_d Wp[c'][h*48+d] attn[bh][d][e] ------
// NO __launch_bounds__: res[12][6]+wv[12] ~ 140 live VGPRs; the old (256,2)
// cap at 128 risked silent spills.
__global__ void k_weff(
    const float* __restrict__ attn_f, const void* __restrict__ Wp,
    bf16_t* __restrict__ Weff, const int* __restrict__ flagp) {
  __shared__ float attn_sm[2304];
  const int isb = *flagp;
  const int b = blockIdx.x >> 3, h = blockIdx.x & 7;
  const int tid = threadIdx.x, bh = b * 8 + h;
  for (int i = tid; i < 2304; i += 256) attn_sm[i] = attn_f[bh * 2304 + i];
  __syncthreads();
  const int cb = tid >> 3, eb = tid & 7;
  float res[12][6];
#pragma unroll
  for (int u = 0; u < 12; u++)
#pragma unroll
    for (int v = 0; v < 6; v++) res[u][v] = 0.f;

  for (int d8 = 0; d8 < 6; d8++) {
    bf16x8 wv[12];
#pragma unroll
    for (int u = 0; u < 12; u++) {
      const int idx = (cb * 12 + u) * CDIM + h * 48 + d8 * 8;
      wv[u] = isb ? load8<true>(Wp, idx) : load8<false>(Wp, idx);
    }
#pragma unroll
    for (int dd = 0; dd < 8; dd++) {
      float wf[12];
#pragma unroll
      for (int u = 0; u < 12; u++) wf[u] = (float)wv[u][dd];
      const int d = d8 * 8 + dd;
#pragma unroll
      for (int v = 0; v < 6; v++) {
        const float a = attn_sm[d * 48 + eb * 6 + v];
#pragma unroll
        for (int u = 0; u < 12; u++) res[u][v] += wf[u] * a;
      }
    }
  }
#pragma unroll
  for (int u = 0; u < 12; u++)
#pragma unroll
    for (int v = 0; v < 6; v++)
      Weff[b * 147456 + (cb * 12 + u) * CDIM + h * 48 + eb * 6 + v] = (bf16_t)res[u][v];
}

// ---------------- K5: out[b,n,c'] = sum_c Weff_b[c'][c] V[b,n,c] + bias[c'] --------
// Grid (64 nt, 8 b, 3 ct). Always-bf16 staging (Weff/V are internal bf16).
// NO __launch_bounds__ (same spill reasoning as k_gemm_qkv).
__global__ void k_gemm_out(
    const bf16_t* __restrict__ Weff, const bf16_t* __restrict__ qkv,
    const void* __restrict__ bias, void* __restrict__ out, const int* __restrict__ flagp) {
  __shared__ __align__(16) bf16_t As[128 * 32];
  __shared__ __align__(16) bf16_t Bs[128 * 32];
  const int isb = *flagp;
  const int tid = threadIdx.x;
  const int lane = tid & 63;
  const int wr = tid >> 7, wc = (tid >> 6) & 1;
  const int q4 = lane >> 4, l16 = lane & 15;
  const int b = blockIdx.y;
  const int rowB0 = blockIdx.x * 128;  // n tile
  const int rowA0 = blockIdx.z * 128;  // c' tile
  const bf16_t* Aa = Weff + b * 147456;
  const bf16_t* Ba = qkv + 2 * WH + b * (NTOK * CDIM);
  const int r0 = tid >> 2, kk = (tid & 3) << 3;

  f32x4 acc[4][4];
#pragma unroll
  for (int i = 0; i < 4; i++)
#pragma unroll
    for (int j = 0; j < 4; j++) acc[i][j] = (f32x4){0.f, 0.f, 0.f, 0.f};

  for (int k0 = 0; k0 < CDIM; k0 += 32) {
    __syncthreads();
    gload16(As + tid * 8,         Aa + (rowA0 + r0) * CDIM + k0 + kk);
    gload16(As + (tid + 256) * 8, Aa + (rowA0 + r0 + 64) * CDIM + k0 + kk);
    gload16(Bs + tid * 8,         Ba + (rowB0 + r0) * CDIM + k0 + kk);
    gload16(Bs + (tid + 256) * 8, Ba + (rowB0 + r0 + 64) * CDIM + k0 + kk);
    __syncthreads();
    bf16x8 af[4], bfr[4];
#pragma unroll
    for (int i = 0; i < 4; i++) {
      af[i]  = *(const bf16x8*)&As[(wr * 64 + i * 16 + l16) * 32 + q4 * 8];
      bfr[i] = *(const bf16x8*)&Bs[(wc * 64 + i * 16 + l16) * 32 + q4 * 8];
    }
#pragma unroll
    for (int i = 0; i < 4; i++)
#pragma unroll
      for (int j = 0; j < 4; j++) acc[i][j] = mfma16(af[i], bfr[j], acc[i][j]);
  }

#pragma unroll
  for (int i = 0; i < 4; i++) {
    const int cg = rowA0 + wr * 64 + i * 16 + q4 * 4;
    float bv[4];
#pragma unroll
    for (int r = 0; r < 4; r++)
      bv[r] = isb ? (float)((const bf16_t*)bias)[cg + r] : ((const float*)bias)[cg + r];
#pragma unroll
    for (int j = 0; j < 4; j++) {
      const int ng = rowB0 + wc * 64 + j * 16 + l16;
      const int oi = (b * NTOK + ng) * CDIM + cg;
      if (isb) {
        bf16x4 o = {(bf16_t)(acc[i][j][0] + bv[0]), (bf16_t)(acc[i][j][1] + bv[1]),
                    (bf16_t)(acc[i][j][2] + bv[2]), (bf16_t)(acc[i][j][3] + bv[3])};
        *(bf16x4*)((bf16_t*)out + oi) = o;
      } else {
        f32x4 o = {acc[i][j][0] + bv[0], acc[i][j][1] + bv[1],
                   acc[i][j][2] + bv[2], acc[i][j][3] + bv[3]};
        *(f32x4*)((float*)out + oi) = o;
      }
    }
  }
}

extern "C" void kernel_launch(void* const* d_in, const int* in_sizes, int n_in,
                              void* d_out, int out_size, void* d_ws, size_t ws_size,
                              hipStream_t stream) {
  (void)in_sizes; (void)n_in; (void)out_size;
  const void* X    = d_in[0];
  const void* Wqkv = d_in[1];
  const void* Wp   = d_in[2];
  const void* bias = d_in[3];

  char* ws = (char*)d_ws;
  bf16_t* qkv    = (bf16_t*)ws;                     // 3*WH bf16 = 150,994,944 B
  float*  S_acc  = (float*)(ws + 150994944);        // 64*2304 f32
  float*  ssq    = (float*)(ws + 151584768);        // 64*96 f32
  float*  attn_f = (float*)(ws + 151609344);        // 64*2304 f32
  bf16_t* Weff   = (bf16_t*)(ws + 152199168);       // 8*384*384 bf16
  int*    flag   = (int*)(ws + 154558464);
  bf16_t* Xb     = (bf16_t*)(ws + 154558720);       // 50,331,648 B
  bf16_t* Wb     = (bf16_t*)(ws + 204890368);       // 884,736 B -> end 205,775,104

  const bool have_cvt_ws = ws_size >= 205775104ULL;

  k_probe<<<dim3(1), 256, 0, stream>>>((const uint32_t*)X, flag);
  k_zero<<<dim3(600), 256, 0, stream>>>(S_acc, 153600);
  if (have_cvt_ws) {
    k_cvt<<<dim3(2048), 256, 0, stream>>>(X, Wqkv, Xb, Wb, flag);
    k_gemm_qkv<<<dim3(512, 3), 256, 0, stream>>>(Xb, Wb, qkv);
  } else {
    k_gemm_qkv_bf16<<<dim3(512, 3), 256, 0, stream>>>(X, Wqkv, qkv, flag);
    k_gemm_qkv_f32<<<dim3(512, 3), 256, 0, stream>>>(X, Wqkv, qkv, flag);
  }
  k_gram<<<dim3(8, 64), 256, 0, stream>>>(qkv, S_acc, ssq);
  k_softmax<<<dim3(64), 64, 0, stream>>>(S_acc, ssq, attn_f);
  k_weff<<<dim3(64), 256, 0, stream>>>(attn_f, Wp, Weff, flag);
  k_gemm_out<<<dim3(64, 8, 3), 256, 0, stream>>>(Weff, qkv, bias, d_out, flag);
}

// Round 5
// 988.802 us; speedup vs baseline: 1.0054x; 1.0054x over previous
//
#include <hip/hip_runtime.h>
#include <hip/hip_bf16.h>
#include <stdint.h>

// XCA (cross-covariance attention), B=8 N=8192 C=384 H=8 Dh=48.
// R8: R7 disproved the spill theory (no launch_bounds -> SAME VGPR=64, SAME
// 2.46 GB/dispatch). Real cause: global_load_lds staging + tile-re-read
// schedule. The DMA path's re-reads are not cache-absorbed (R0 reg-staging:
// 885MB issued -> 56MB FETCH; R5/R7 gload_lds: ~885MB issued -> 1.1GB FETCH),
// and the read thrash evicts partial output lines -> symmetric write RMW
// amplification (147MB -> 1.3GB).
// Fix: REG-STAGING everywhere (R0/R1-proven exact traffic). Keep: k_cvt bf16
// inputs (half the staging bytes), grid-y=3 split (1536 blocks, no bounds ->
// ~120 VGPR -> 4 blocks/CU), swapped-operand q/k MFMA + bf16x4 stores (R1-
// validated on hardware).

typedef __bf16 bf16_t;
typedef __attribute__((ext_vector_type(8))) __bf16 bf16x8;
typedef __attribute__((ext_vector_type(4))) __bf16 bf16x4;
typedef __attribute__((ext_vector_type(4))) float f32x4;

#define NTOK 8192
#define CDIM 384
#define WH   25165824   // 8*8*48*8192 elements per q/k plane
#define DHN  393216     // 48*8192

#define XCHUNKS 3145728   // 25,165,824 X elems / 8
#define TCHUNKS 3201024   // + 442,368 W elems / 8

__device__ __forceinline__ f32x4 mfma16(bf16x8 a, bf16x8 b, f32x4 c) {
  return __builtin_amdgcn_mfma_f32_16x16x32_bf16(a, b, c, 0, 0, 0);
}

template <bool BF16>
__device__ __forceinline__ bf16x8 load8(const void* p, int idx) {
  if constexpr (BF16) {
    return *(const bf16x8*)((const bf16_t*)p + idx);
  } else {
    const float* f = (const float*)p + idx;
    f32x4 a = *(const f32x4*)f;
    f32x4 b = *(const f32x4*)(f + 4);
    bf16x8 r;
    r[0] = (bf16_t)a[0]; r[1] = (bf16_t)a[1]; r[2] = (bf16_t)a[2]; r[3] = (bf16_t)a[3];
    r[4] = (bf16_t)b[0]; r[5] = (bf16_t)b[1]; r[6] = (bf16_t)b[2]; r[7] = (bf16_t)b[3];
    return r;
  }
}

// ---------------- probe: are inputs bf16 (1) or f32 (0)? ----------------
__global__ void k_probe(const uint32_t* __restrict__ X, int* __restrict__ flag) {
  __shared__ int cnt;
  if (threadIdx.x == 0) cnt = 0;
  __syncthreads();
  const uint32_t w = X[threadIdx.x];
  const int e = (int)((w >> 7) & 0xFF);  // exponent of low-16 as bf16
  const int sane = (e >= 110 && e <= 131) ? 1 : 0;
  atomicAdd(&cnt, sane);
  __syncthreads();
  if (threadIdx.x == 0) *flag = (cnt >= 128) ? 1 : 0;
}

// ---------------- zero fp32 accumulators ----------------
__global__ void k_zero(float* __restrict__ p, int n) {
  int i = blockIdx.x * 256 + threadIdx.x;
  if (i < n) p[i] = 0.f;
}

// ---------------- cvt: X,Wqkv (f32 or bf16) -> bf16 workspace ----------------
__global__ void k_cvt(const void* __restrict__ X, const void* __restrict__ Wqkv,
                      bf16_t* __restrict__ Xb, bf16_t* __restrict__ Wb,
                      const int* __restrict__ flagp) {
  const int isb = *flagp;
  const int G = gridDim.x * 256;
  for (int c = blockIdx.x * 256 + threadIdx.x; c < TCHUNKS; c += G) {
    const bool isX = c < XCHUNKS;
    const int lc = isX ? c : c - XCHUNKS;          // chunk within its buffer
    const void* src = isX ? X : Wqkv;
    bf16_t* dst = (isX ? Xb : Wb) + (size_t)lc * 8;
    if (isb) {
      *(bf16x8*)dst = *((const bf16x8*)src + lc);
    } else {
      const f32x4 a = *((const f32x4*)src + lc * 2);
      const f32x4 b = *((const f32x4*)src + lc * 2 + 1);
      bf16x8 r;
      r[0] = (bf16_t)a[0]; r[1] = (bf16_t)a[1]; r[2] = (bf16_t)a[2]; r[3] = (bf16_t)a[3];
      r[4] = (bf16_t)b[0]; r[5] = (bf16_t)b[1]; r[6] = (bf16_t)b[2]; r[7] = (bf16_t)b[3];
      *(bf16x8*)dst = r;
    }
  }
}

// ---------------- K1: qkv = x @ w_qkv^T ----------------
// Grid (512 m-tiles, 3). blockIdx.y = which (0=q,1=k,2=v); 3 jt per block.
// REG-STAGED (global -> VGPR -> LDS): cache hierarchy absorbs the jtt/grid-y
// B-tile re-reads (R0/R1-proven). q/k tiles use swapped MFMA (D row = token)
// -> bf16x4 stores along N; v original order -> bf16x4 stores along C.
template <bool BF16>
__device__ __forceinline__ void qkv_body(const void* __restrict__ X,
                                         const void* __restrict__ Wqkv,
                                         bf16_t* __restrict__ qkv,
                                         bf16_t* As, bf16_t* Bs) {
  const int tid = threadIdx.x;
  const int lane = tid & 63;
  const int wr = tid >> 7, wc = (tid >> 6) & 1;
  const int q4 = lane >> 4, l16 = lane & 15;
  const int which = blockIdx.y;
  const int rowB0 = blockIdx.x * 128;
  const int r0 = tid >> 2, kk = (tid & 3) << 3;
  const int bb = rowB0 >> 13;       // batch index (tiles never cross b)
  const int nB = rowB0 & 8191;      // token base within batch

  for (int jtt = 0; jtt < 3; jtt++) {
    const int rowA0 = (which * 3 + jtt) * 128;
    f32x4 acc[4][4];
#pragma unroll
    for (int i = 0; i < 4; i++)
#pragma unroll
      for (int j = 0; j < 4; j++) acc[i][j] = (f32x4){0.f, 0.f, 0.f, 0.f};

    for (int k0 = 0; k0 < CDIM; k0 += 32) {
      bf16x8 a0 = load8<BF16>(Wqkv, (rowA0 + r0) * CDIM + k0 + kk);
      bf16x8 a1 = load8<BF16>(Wqkv, (rowA0 + r0 + 64) * CDIM + k0 + kk);
      bf16x8 b0 = load8<BF16>(X, (rowB0 + r0) * CDIM + k0 + kk);
      bf16x8 b1 = load8<BF16>(X, (rowB0 + r0 + 64) * CDIM + k0 + kk);
      __syncthreads();  // prior iteration's LDS frag reads complete
      *(bf16x8*)&As[tid * 8] = a0;
      *(bf16x8*)&As[(tid + 256) * 8] = a1;
      *(bf16x8*)&Bs[tid * 8] = b0;
      *(bf16x8*)&Bs[(tid + 256) * 8] = b1;
      __syncthreads();
      bf16x8 af[4], bfr[4];
#pragma unroll
      for (int i = 0; i < 4; i++) {
        af[i]  = *(const bf16x8*)&As[(wr * 64 + i * 16 + l16) * 32 + q4 * 8];
        bfr[i] = *(const bf16x8*)&Bs[(wc * 64 + i * 16 + l16) * 32 + q4 * 8];
      }
      if (which < 2) {
#pragma unroll
        for (int i = 0; i < 4; i++)
#pragma unroll
          for (int j = 0; j < 4; j++) acc[i][j] = mfma16(bfr[j], af[i], acc[i][j]);
      } else {
#pragma unroll
        for (int i = 0; i < 4; i++)
#pragma unroll
          for (int j = 0; j < 4; j++) acc[i][j] = mfma16(af[i], bfr[j], acc[i][j]);
      }
    }

    if (which < 2) {
      // swapped: acc[i][j][r] = D[token = rowB0+wc*64+j*16+q4*4+r][ch = rowA0+wr*64+i*16+l16]
#pragma unroll
      for (int i = 0; i < 4; i++) {
        const int rin = jtt * 128 + wr * 64 + i * 16 + l16;  // channel within plane
        const int h = rin / 48, dh = rin - h * 48;
        bf16_t* rowp = qkv + which * WH + (bb * 8 + h) * DHN + dh * NTOK
                       + nB + wc * 64 + q4 * 4;
#pragma unroll
        for (int j = 0; j < 4; j++) {
          bf16x4 o = {(bf16_t)acc[i][j][0], (bf16_t)acc[i][j][1],
                      (bf16_t)acc[i][j][2], (bf16_t)acc[i][j][3]};
          *(bf16x4*)(rowp + j * 16) = o;
        }
      }
    } else {
      // original: acc[i][j][r] = D[ch = rowA0+wr*64+i*16+q4*4+r][token = rowB0+wc*64+j*16+l16]
#pragma unroll
      for (int i = 0; i < 4; i++) {
        const int rin0 = jtt * 128 + wr * 64 + i * 16 + q4 * 4;  // c within v
#pragma unroll
        for (int j = 0; j < 4; j++) {
          const int mg = rowB0 + wc * 64 + j * 16 + l16;
          bf16x4 o = {(bf16_t)acc[i][j][0], (bf16_t)acc[i][j][1],
                      (bf16_t)acc[i][j][2], (bf16_t)acc[i][j][3]};
          *(bf16x4*)(qkv + 2 * WH + mg * CDIM + rin0) = o;
        }
      }
    }
  }
}

// main path: inputs already bf16 in workspace. No launch_bounds (natural
// VGPR ~120 -> 4 waves/SIMD -> 4 blocks/CU with grid 1536).
__global__ void k_gemm_qkv(
    const bf16_t* __restrict__ Xb, const bf16_t* __restrict__ Wb,
    bf16_t* __restrict__ qkv) {
  __shared__ __align__(16) bf16_t As[128 * 32];
  __shared__ __align__(16) bf16_t Bs[128 * 32];
  qkv_body<true>(Xb, Wb, qkv, As, Bs);
}

// fallback path (ws too small for cvt buffers): flag-gated pair on raw inputs.
__global__ void k_gemm_qkv_bf16(
    const void* __restrict__ X, const void* __restrict__ Wqkv,
    bf16_t* __restrict__ qkv, const int* __restrict__ flagp) {
  __shared__ __align__(16) bf16_t As[128 * 32];
  __shared__ __align__(16) bf16_t Bs[128 * 32];
  if (!*flagp) return;
  qkv_body<true>(X, Wqkv, qkv, As, Bs);
}

__global__ void k_gemm_qkv_f32(
    const void* __restrict__ X, const void* __restrict__ Wqkv,
    bf16_t* __restrict__ qkv, const int* __restrict__ flagp) {
  __shared__ __align__(16) bf16_t As[128 * 32];
  __shared__ __align__(16) bf16_t Bs[128 * 32];
  if (*flagp) return;
  qkv_body<false>(X, Wqkv, qkv, As, Bs);
}

// ---------------- K2: Gram S=Q K^T + sumsq ----------------
__global__ __launch_bounds__(256, 2) void k_gram(
    const bf16_t* __restrict__ qkv, float* __restrict__ S_acc, float* __restrict__ ssq_acc) {
  __shared__ __align__(16) float sm[9312];  // 37,248 B
  bf16_t* Qs = (bf16_t*)sm;                 // 6144 bf16 = [4][48][32]
  bf16_t* Ks = Qs + 6144;
  float* ssq_sm = sm + 9216;                // 96 floats

  const int tid = threadIdx.x;
  const int wave = tid >> 6, lane = tid & 63, q4 = lane >> 4, l16 = lane & 15;
  const int s = blockIdx.x, bh = blockIdx.y;
  const bf16_t* Qg = qkv + bh * DHN;
  const bf16_t* Kg = qkv + WH + bh * DHN;

  if (tid < 96) ssq_sm[tid] = 0.f;

  f32x4 acc[3][3];
#pragma unroll
  for (int i = 0; i < 3; i++)
#pragma unroll
    for (int j = 0; j < 3; j++) acc[i][j] = (f32x4){0.f, 0.f, 0.f, 0.f};
  float qss[3] = {0.f, 0.f, 0.f}, kss[3] = {0.f, 0.f, 0.f};

  for (int t0 = 0; t0 < 8; t0++) {
    const int n0 = s * 1024 + t0 * 128;
    bf16x8 qv[3], kv[3];
#pragma unroll
    for (int jj = 0; jj < 3; jj++) {
      const int c = jj * 256 + tid;
      const int st = c / 192, rem = c - st * 192;
      const int row = rem >> 2, kk = (rem & 3) << 3;
      const int gofs = row * NTOK + n0 + st * 32 + kk;
      qv[jj] = *(const bf16x8*)(Qg + gofs);
      kv[jj] = *(const bf16x8*)(Kg + gofs);
    }
    __syncthreads();
#pragma unroll
    for (int jj = 0; jj < 3; jj++) {
      *(bf16x8*)&Qs[(jj * 256 + tid) * 8] = qv[jj];
      *(bf16x8*)&Ks[(jj * 256 + tid) * 8] = kv[jj];
    }
    __syncthreads();
    bf16x8 qf[3], kf[3];
#pragma unroll
    for (int i = 0; i < 3; i++) {
      qf[i] = *(const bf16x8*)&Qs[wave * 1536 + (i * 16 + l16) * 32 + q4 * 8];
      kf[i] = *(const bf16x8*)&Ks[wave * 1536 + (i * 16 + l16) * 32 + q4 * 8];
    }
#pragma unroll
    for (int i = 0; i < 3; i++) {
#pragma unroll
      for (int u = 0; u < 8; u++) {
        const float qv2 = (float)qf[i][u], kv2 = (float)kf[i][u];
        qss[i] += qv2 * qv2;
        kss[i] += kv2 * kv2;
      }
#pragma unroll
      for (int j = 0; j < 3; j++) acc[i][j] = mfma16(qf[i], kf[j], acc[i][j]);
    }
  }

  __syncthreads();
  float* red = sm;  // 4 waves x 2304 fp32
#pragma unroll
  for (int i = 0; i < 3; i++)
#pragma unroll
    for (int j = 0; j < 3; j++)
#pragma unroll
      for (int r = 0; r < 4; r++)
        red[wave * 2304 + (i * 3 + j) * 256 + lane * 4 + r] = acc[i][j][r];
#pragma unroll
  for (int i = 0; i < 3; i++) {
    atomicAdd(&ssq_sm[i * 16 + l16], qss[i]);
    atomicAdd(&ssq_sm[48 + i * 16 + l16], kss[i]);
  }
  __syncthreads();
  for (int idx = tid; idx < 2304; idx += 256) {
    const float v = red[idx] + red[2304 + idx] + red[4608 + idx] + red[6912 + idx];
    const int tile = idx >> 8, ln = (idx >> 2) & 63, r = idx & 3;
    const int i = tile / 3, j = tile - i * 3;
    const int d = i * 16 + ((ln >> 4) << 2) + r;
    const int e = j * 16 + (ln & 15);
    atomicAdd(&S_acc[bh * 2304 + d * 48 + e], v);
  }
  if (tid < 96) atomicAdd(&ssq_acc[bh * 96 + tid], ssq_sm[tid]);
}

// ---------------- K3: softmax(S / (|q_d||k_e|)) ----------------
__global__ void k_softmax(const float* __restrict__ S_acc, const float* __restrict__ ssq_acc,
                          float* __restrict__ attn_f) {
  __shared__ float invk_sm[48];
  const int bh = blockIdx.x, d = threadIdx.x;
  if (d < 48) invk_sm[d] = 1.f / fmaxf(sqrtf(ssq_acc[bh * 96 + 48 + d]), 1e-12f);
  __syncthreads();
  if (d < 48) {
    const float invq = 1.f / fmaxf(sqrtf(ssq_acc[bh * 96 + d]), 1e-12f);
    float lg[48], mx = -1e30f;
#pragma unroll
    for (int e = 0; e < 48; e++) {
      lg[e] = S_acc[bh * 2304 + d * 48 + e] * invq * invk_sm[e];
      mx = fmaxf(mx, lg[e]);
    }
    float ssum = 0.f;
#pragma unroll
    for (int e = 0; e < 48; e++) { lg[e] = expf(lg[e] - mx); ssum += lg[e]; }
    const float inv = 1.f / ssum;
#pragma unroll
    for (int e = 0; e < 48; e++) attn_f[bh * 2304 + d * 48 + e] = lg[e] * inv;
  }
}

// ---------------- K4: Weff_b[c'][h*48+e] = sum_d Wp[c'][h*48+d] attn[bh][d][e] ------
__global__ void k_weff(
    const float* __restrict__ attn_f, const void* __restrict__ Wp,
    bf16_t* __restrict__ Weff, const int* __restrict__ flagp) {
  __shared__ float attn_sm[2304];
  const int isb = *flagp;
  const int b = blockIdx.x >> 3, h = blockIdx.x & 7;
  const int tid = threadIdx.x, bh = b * 8 + h;
  for (int i = tid; i < 2304; i += 256) attn_sm[i] = attn_f[bh * 2304 + i];
  __syncthreads();
  const int cb = tid >> 3, eb = tid & 7;
  float res[12][6];
#pragma unroll
  for (int u = 0; u < 12; u++)
#pragma unroll
    for (int v = 0; v < 6; v++) res[u][v] = 0.f;

  for (int d8 = 0; d8 < 6; d8++) {
    bf16x8 wv[12];
#pragma unroll
    for (int u = 0; u < 12; u++) {
      const int idx = (cb * 12 + u) * CDIM + h * 48 + d8 * 8;
      wv[u] = isb ? load8<true>(Wp, idx) : load8<false>(Wp, idx);
    }
#pragma unroll
    for (int dd = 0; dd < 8; dd++) {
      float wf[12];
#pragma unroll
      for (int u = 0; u < 12; u++) wf[u] = (float)wv[u][dd];
      const int d = d8 * 8 + dd;
#pragma unroll
      for (int v = 0; v < 6; v++) {
        const float a = attn_sm[d * 48 + eb * 6 + v];
#pragma unroll
        for (int u = 0; u < 12; u++) res[u][v] += wf[u] * a;
      }
    }
  }
#pragma unroll
  for (int u = 0; u < 12; u++)
#pragma unroll
    for (int v = 0; v < 6; v++)
      Weff[b * 147456 + (cb * 12 + u) * CDIM + h * 48 + eb * 6 + v] = (bf16_t)res[u][v];
}

// ---------------- K5: out[b,n,c'] = sum_c Weff_b[c'][c] V[b,n,c] + bias[c'] --------
// Grid (64 nt, 8 b, 3 ct). REG-STAGED bf16 (Weff/V are internal bf16).
__global__ void k_gemm_out(
    const bf16_t* __restrict__ Weff, const bf16_t* __restrict__ qkv,
    const void* __restrict__ bias, void* __restrict__ out, const int* __restrict__ flagp) {
  __shared__ __align__(16) bf16_t As[128 * 32];
  __shared__ __align__(16) bf16_t Bs[128 * 32];
  const int isb = *flagp;
  const int tid = threadIdx.x;
  const int lane = tid & 63;
  const int wr = tid >> 7, wc = (tid >> 6) & 1;
  const int q4 = lane >> 4, l16 = lane & 15;
  const int b = blockIdx.y;
  const int rowB0 = blockIdx.x * 128;  // n tile
  const int rowA0 = blockIdx.z * 128;  // c' tile
  const bf16_t* Aa = Weff + b * 147456;
  const bf16_t* Ba = qkv + 2 * WH + b * (NTOK * CDIM);
  const int r0 = tid >> 2, kk = (tid & 3) << 3;

  f32x4 acc[4][4];
#pragma unroll
  for (int i = 0; i < 4; i++)
#pragma unroll
    for (int j = 0; j < 4; j++) acc[i][j] = (f32x4){0.f, 0.f, 0.f, 0.f};

  for (int k0 = 0; k0 < CDIM; k0 += 32) {
    bf16x8 a0 = *(const bf16x8*)(Aa + (rowA0 + r0) * CDIM + k0 + kk);
    bf16x8 a1 = *(const bf16x8*)(Aa + (rowA0 + r0 + 64) * CDIM + k0 + kk);
    bf16x8 b0 = *(const bf16x8*)(Ba + (rowB0 + r0) * CDIM + k0 + kk);
    bf16x8 b1 = *(const bf16x8*)(Ba + (rowB0 + r0 + 64) * CDIM + k0 + kk);
    __syncthreads();
    *(bf16x8*)&As[tid * 8] = a0;
    *(bf16x8*)&As[(tid + 256) * 8] = a1;
    *(bf16x8*)&Bs[tid * 8] = b0;
    *(bf16x8*)&Bs[(tid + 256) * 8] = b1;
    __syncthreads();
    bf16x8 af[4], bfr[4];
#pragma unroll
    for (int i = 0; i < 4; i++) {
      af[i]  = *(const bf16x8*)&As[(wr * 64 + i * 16 + l16) * 32 + q4 * 8];
      bfr[i] = *(const bf16x8*)&Bs[(wc * 64 + i * 16 + l16) * 32 + q4 * 8];
    }
#pragma unroll
    for (int i = 0; i < 4; i++)
#pragma unroll
      for (int j = 0; j < 4; j++) acc[i][j] = mfma16(af[i], bfr[j], acc[i][j]);
  }

#pragma unroll
  for (int i = 0; i < 4; i++) {
    const int cg = rowA0 + wr * 64 + i * 16 + q4 * 4;
    float bv[4];
#pragma unroll
    for (int r = 0; r < 4; r++)
      bv[r] = isb ? (float)((const bf16_t*)bias)[cg + r] : ((const float*)bias)[cg + r];
#pragma unroll
    for (int j = 0; j < 4; j++) {
      const int ng = rowB0 + wc * 64 + j * 16 + l16;
      const int oi = (b * NTOK + ng) * CDIM + cg;
      if (isb) {
        bf16x4 o = {(bf16_t)(acc[i][j][0] + bv[0]), (bf16_t)(acc[i][j][1] + bv[1]),
                    (bf16_t)(acc[i][j][2] + bv[2]), (bf16_t)(acc[i][j][3] + bv[3])};
        *(bf16x4*)((bf16_t*)out + oi) = o;
      } else {
        f32x4 o = {acc[i][j][0] + bv[0], acc[i][j][1] + bv[1],
                   acc[i][j][2] + bv[2], acc[i][j][3] + bv[3]};
        *(f32x4*)((float*)out + oi) = o;
      }
    }
  }
}

extern "C" void kernel_launch(void* const* d_in, const int* in_sizes, int n_in,
                              void* d_out, int out_size, void* d_ws, size_t ws_size,
                              hipStream_t stream) {
  (void)in_sizes; (void)n_in; (void)out_size;
  const void* X    = d_in[0];
  const void* Wqkv = d_in[1];
  const void* Wp   = d_in[2];
  const void* bias = d_in[3];

  char* ws = (char*)d_ws;
  bf16_t* qkv    = (bf16_t*)ws;                     // 3*WH bf16 = 150,994,944 B
  float*  S_acc  = (float*)(ws + 150994944);        // 64*2304 f32
  float*  ssq    = (float*)(ws + 151584768);        // 64*96 f32
  float*  attn_f = (float*)(ws + 151609344);        // 64*2304 f32
  bf16_t* Weff   = (bf16_t*)(ws + 152199168);       // 8*384*384 bf16
  int*    flag   = (int*)(ws + 154558464);
  bf16_t* Xb     = (bf16_t*)(ws + 154558720);       // 50,331,648 B
  bf16_t* Wb     = (bf16_t*)(ws + 204890368);       // 884,736 B -> end 205,775,104

  const bool have_cvt_ws = ws_size >= 205775104ULL;

  k_probe<<<dim3(1), 256, 0, stream>>>((const uint32_t*)X, flag);
  k_zero<<<dim3(600), 256, 0, stream>>>(S_acc, 153600);
  if (have_cvt_ws) {
    k_cvt<<<dim3(2048), 256, 0, stream>>>(X, Wqkv, Xb, Wb, flag);
    k_gemm_qkv<<<dim3(512, 3), 256, 0, stream>>>(Xb, Wb, qkv);
  } else {
    k_gemm_qkv_bf16<<<dim3(512, 3), 256, 0, stream>>>(X, Wqkv, qkv, flag);
    k_gemm_qkv_f32<<<dim3(512, 3), 256, 0, stream>>>(X, Wqkv, qkv, flag);
  }
  k_gram<<<dim3(8, 64), 256, 0, stream>>>(qkv, S_acc, ssq);
  k_softmax<<<dim3(64), 64, 0, stream>>>(S_acc, ssq, attn_f);
  k_weff<<<dim3(64), 256, 0, stream>>>(attn_f, Wp, Weff, flag);
  k_gemm_out<<<dim3(64, 8, 3), 256, 0, stream>>>(Weff, qkv, bias, d_out, flag);
}

// Round 6
// 496.753 us; speedup vs baseline: 2.0012x; 1.9905x over previous
//
#include <hip/hip_runtime.h>
#include <hip/hip_bf16.h>
#include <stdint.h>

// XCA (cross-covariance attention), B=8 N=8192 C=384 H=8 Dh=48.
// R9: concurrency was the toxin. Evidence: R0 (jt-inside, 2 blocks/CU) =
// 56MB FETCH / 150MB WRITE exact / 207us; R5/R7/R8 (y-split, 4-8 blocks/CU,
// any staging path) = 0.8-1.1GB FETCH (zero cache absorption) + 1.3-1.45GB
// WRITE (partial-sector eviction RMW) / 600-700us. This GEMM is cache-
// locality-bound: tile re-reads only get absorbed when few blocks stream
// concurrently. Revert to R0 schedule (jt=0..8 inside, 512 blocks,
// launch_bounds(256,2), reg-staging). Keep the two proven wins:
//   - k_cvt f32->bf16 input pass (halves staging bytes, removes cvt ALU)
//   - swapped-operand q/k MFMA -> bf16x4 stores (R1-validated)
// k_gemm_out likewise reverted to ct-inside, bounds(256,2).

typedef __bf16 bf16_t;
typedef __attribute__((ext_vector_type(8))) __bf16 bf16x8;
typedef __attribute__((ext_vector_type(4))) __bf16 bf16x4;
typedef __attribute__((ext_vector_type(4))) float f32x4;

#define NTOK 8192
#define CDIM 384
#define WH   25165824   // 8*8*48*8192 elements per q/k plane
#define DHN  393216     // 48*8192

#define XCHUNKS 3145728   // 25,165,824 X elems / 8
#define TCHUNKS 3201024   // + 442,368 W elems / 8

__device__ __forceinline__ f32x4 mfma16(bf16x8 a, bf16x8 b, f32x4 c) {
  return __builtin_amdgcn_mfma_f32_16x16x32_bf16(a, b, c, 0, 0, 0);
}

template <bool BF16>
__device__ __forceinline__ bf16x8 load8(const void* p, int idx) {
  if constexpr (BF16) {
    return *(const bf16x8*)((const bf16_t*)p + idx);
  } else {
    const float* f = (const float*)p + idx;
    f32x4 a = *(const f32x4*)f;
    f32x4 b = *(const f32x4*)(f + 4);
    bf16x8 r;
    r[0] = (bf16_t)a[0]; r[1] = (bf16_t)a[1]; r[2] = (bf16_t)a[2]; r[3] = (bf16_t)a[3];
    r[4] = (bf16_t)b[0]; r[5] = (bf16_t)b[1]; r[6] = (bf16_t)b[2]; r[7] = (bf16_t)b[3];
    return r;
  }
}

// ---------------- probe: are inputs bf16 (1) or f32 (0)? ----------------
__global__ void k_probe(const uint32_t* __restrict__ X, int* __restrict__ flag) {
  __shared__ int cnt;
  if (threadIdx.x == 0) cnt = 0;
  __syncthreads();
  const uint32_t w = X[threadIdx.x];
  const int e = (int)((w >> 7) & 0xFF);  // exponent of low-16 as bf16
  const int sane = (e >= 110 && e <= 131) ? 1 : 0;
  atomicAdd(&cnt, sane);
  __syncthreads();
  if (threadIdx.x == 0) *flag = (cnt >= 128) ? 1 : 0;
}

// ---------------- zero fp32 accumulators ----------------
__global__ void k_zero(float* __restrict__ p, int n) {
  int i = blockIdx.x * 256 + threadIdx.x;
  if (i < n) p[i] = 0.f;
}

// ---------------- cvt: X,Wqkv (f32 or bf16) -> bf16 workspace ----------------
__global__ void k_cvt(const void* __restrict__ X, const void* __restrict__ Wqkv,
                      bf16_t* __restrict__ Xb, bf16_t* __restrict__ Wb,
                      const int* __restrict__ flagp) {
  const int isb = *flagp;
  const int G = gridDim.x * 256;
  for (int c = blockIdx.x * 256 + threadIdx.x; c < TCHUNKS; c += G) {
    const bool isX = c < XCHUNKS;
    const int lc = isX ? c : c - XCHUNKS;          // chunk within its buffer
    const void* src = isX ? X : Wqkv;
    bf16_t* dst = (isX ? Xb : Wb) + (size_t)lc * 8;
    if (isb) {
      *(bf16x8*)dst = *((const bf16x8*)src + lc);
    } else {
      const f32x4 a = *((const f32x4*)src + lc * 2);
      const f32x4 b = *((const f32x4*)src + lc * 2 + 1);
      bf16x8 r;
      r[0] = (bf16_t)a[0]; r[1] = (bf16_t)a[1]; r[2] = (bf16_t)a[2]; r[3] = (bf16_t)a[3];
      r[4] = (bf16_t)b[0]; r[5] = (bf16_t)b[1]; r[6] = (bf16_t)b[2]; r[7] = (bf16_t)b[3];
      *(bf16x8*)dst = r;
    }
  }
}

// ---------------- K1: qkv = x @ w_qkv^T ----------------
// Grid (512). jt=0..8 INSIDE the block (R0 schedule): the 98 KB x-tile stays
// L2-resident across all 9 A-tiles; 2 blocks/CU keeps the cache hierarchy
// absorbing the re-reads (R0: 56 MB FETCH vs 885 MB issued).
// q/k tiles (which<2): swapped MFMA (D row = token) -> bf16x4 stores along N.
// v tiles: original order (D row = channel) -> bf16x4 stores along C.
template <bool BF16>
__device__ __forceinline__ void qkv_body(const void* __restrict__ X,
                                         const void* __restrict__ Wqkv,
                                         bf16_t* __restrict__ qkv,
                                         bf16_t* As, bf16_t* Bs) {
  const int tid = threadIdx.x;
  const int lane = tid & 63;
  const int wr = tid >> 7, wc = (tid >> 6) & 1;
  const int q4 = lane >> 4, l16 = lane & 15;
  const int rowB0 = blockIdx.x * 128;
  const int r0 = tid >> 2, kk = (tid & 3) << 3;
  const int bb = rowB0 >> 13;       // batch index (tiles never cross b)
  const int nB = rowB0 & 8191;      // token base within batch

  for (int jt = 0; jt < 9; jt++) {
    const int rowA0 = jt * 128;
    const int which = jt / 3;       // 0=q 1=k 2=v (uniform per jt)
    const int jtt = jt - which * 3;
    f32x4 acc[4][4];
#pragma unroll
    for (int i = 0; i < 4; i++)
#pragma unroll
      for (int j = 0; j < 4; j++) acc[i][j] = (f32x4){0.f, 0.f, 0.f, 0.f};

    for (int k0 = 0; k0 < CDIM; k0 += 32) {
      bf16x8 a0 = load8<BF16>(Wqkv, (rowA0 + r0) * CDIM + k0 + kk);
      bf16x8 a1 = load8<BF16>(Wqkv, (rowA0 + r0 + 64) * CDIM + k0 + kk);
      bf16x8 b0 = load8<BF16>(X, (rowB0 + r0) * CDIM + k0 + kk);
      bf16x8 b1 = load8<BF16>(X, (rowB0 + r0 + 64) * CDIM + k0 + kk);
      __syncthreads();  // prior iteration's LDS frag reads complete
      *(bf16x8*)&As[tid * 8] = a0;
      *(bf16x8*)&As[(tid + 256) * 8] = a1;
      *(bf16x8*)&Bs[tid * 8] = b0;
      *(bf16x8*)&Bs[(tid + 256) * 8] = b1;
      __syncthreads();
      bf16x8 af[4], bfr[4];
#pragma unroll
      for (int i = 0; i < 4; i++) {
        af[i]  = *(const bf16x8*)&As[(wr * 64 + i * 16 + l16) * 32 + q4 * 8];
        bfr[i] = *(const bf16x8*)&Bs[(wc * 64 + i * 16 + l16) * 32 + q4 * 8];
      }
      if (which < 2) {
#pragma unroll
        for (int i = 0; i < 4; i++)
#pragma unroll
          for (int j = 0; j < 4; j++) acc[i][j] = mfma16(bfr[j], af[i], acc[i][j]);
      } else {
#pragma unroll
        for (int i = 0; i < 4; i++)
#pragma unroll
          for (int j = 0; j < 4; j++) acc[i][j] = mfma16(af[i], bfr[j], acc[i][j]);
      }
    }

    if (which < 2) {
      // swapped: acc[i][j][r] = D[token = rowB0+wc*64+j*16+q4*4+r][ch = rowA0+wr*64+i*16+l16]
#pragma unroll
      for (int i = 0; i < 4; i++) {
        const int rin = jtt * 128 + wr * 64 + i * 16 + l16;  // channel within plane
        const int h = rin / 48, dh = rin - h * 48;
        bf16_t* rowp = qkv + which * WH + (bb * 8 + h) * DHN + dh * NTOK
                       + nB + wc * 64 + q4 * 4;
#pragma unroll
        for (int j = 0; j < 4; j++) {
          bf16x4 o = {(bf16_t)acc[i][j][0], (bf16_t)acc[i][j][1],
                      (bf16_t)acc[i][j][2], (bf16_t)acc[i][j][3]};
          *(bf16x4*)(rowp + j * 16) = o;
        }
      }
    } else {
      // original: acc[i][j][r] = D[ch = rowA0+wr*64+i*16+q4*4+r][token = rowB0+wc*64+j*16+l16]
#pragma unroll
      for (int i = 0; i < 4; i++) {
        const int rin0 = jtt * 128 + wr * 64 + i * 16 + q4 * 4;  // c within v
#pragma unroll
        for (int j = 0; j < 4; j++) {
          const int mg = rowB0 + wc * 64 + j * 16 + l16;
          bf16x4 o = {(bf16_t)acc[i][j][0], (bf16_t)acc[i][j][1],
                      (bf16_t)acc[i][j][2], (bf16_t)acc[i][j][3]};
          *(bf16x4*)(qkv + 2 * WH + mg * CDIM + rin0) = o;
        }
      }
    }
  }
}

// main path: inputs already bf16 in workspace. bounds(256,2) proven safe
// (R0 VGPR=120 no spill) and caps concurrency at 2 blocks/CU for absorption.
__global__ __launch_bounds__(256, 2) void k_gemm_qkv(
    const bf16_t* __restrict__ Xb, const bf16_t* __restrict__ Wb,
    bf16_t* __restrict__ qkv) {
  __shared__ __align__(16) bf16_t As[128 * 32];
  __shared__ __align__(16) bf16_t Bs[128 * 32];
  qkv_body<true>(Xb, Wb, qkv, As, Bs);
}

// fallback path (ws too small for cvt buffers): flag-gated pair on raw inputs.
__global__ __launch_bounds__(256, 2) void k_gemm_qkv_bf16(
    const void* __restrict__ X, const void* __restrict__ Wqkv,
    bf16_t* __restrict__ qkv, const int* __restrict__ flagp) {
  __shared__ __align__(16) bf16_t As[128 * 32];
  __shared__ __align__(16) bf16_t Bs[128 * 32];
  if (!*flagp) return;
  qkv_body<true>(X, Wqkv, qkv, As, Bs);
}

__global__ __launch_bounds__(256, 2) void k_gemm_qkv_f32(
    const void* __restrict__ X, const void* __restrict__ Wqkv,
    bf16_t* __restrict__ qkv, const int* __restrict__ flagp) {
  __shared__ __align__(16) bf16_t As[128 * 32];
  __shared__ __align__(16) bf16_t Bs[128 * 32];
  if (*flagp) return;
  qkv_body<false>(X, Wqkv, qkv, As, Bs);
}

// ---------------- K2: Gram S=Q K^T + sumsq ----------------
__global__ __launch_bounds__(256, 2) void k_gram(
    const bf16_t* __restrict__ qkv, float* __restrict__ S_acc, float* __restrict__ ssq_acc) {
  __shared__ __align__(16) float sm[9312];  // 37,248 B
  bf16_t* Qs = (bf16_t*)sm;                 // 6144 bf16 = [4][48][32]
  bf16_t* Ks = Qs + 6144;
  float* ssq_sm = sm + 9216;                // 96 floats

  const int tid = threadIdx.x;
  const int wave = tid >> 6, lane = tid & 63, q4 = lane >> 4, l16 = lane & 15;
  const int s = blockIdx.x, bh = blockIdx.y;
  const bf16_t* Qg = qkv + bh * DHN;
  const bf16_t* Kg = qkv + WH + bh * DHN;

  if (tid < 96) ssq_sm[tid] = 0.f;

  f32x4 acc[3][3];
#pragma unroll
  for (int i = 0; i < 3; i++)
#pragma unroll
    for (int j = 0; j < 3; j++) acc[i][j] = (f32x4){0.f, 0.f, 0.f, 0.f};
  float qss[3] = {0.f, 0.f, 0.f}, kss[3] = {0.f, 0.f, 0.f};

  for (int t0 = 0; t0 < 8; t0++) {
    const int n0 = s * 1024 + t0 * 128;
    bf16x8 qv[3], kv[3];
#pragma unroll
    for (int jj = 0; jj < 3; jj++) {
      const int c = jj * 256 + tid;
      const int st = c / 192, rem = c - st * 192;
      const int row = rem >> 2, kk = (rem & 3) << 3;
      const int gofs = row * NTOK + n0 + st * 32 + kk;
      qv[jj] = *(const bf16x8*)(Qg + gofs);
      kv[jj] = *(const bf16x8*)(Kg + gofs);
    }
    __syncthreads();
#pragma unroll
    for (int jj = 0; jj < 3; jj++) {
      *(bf16x8*)&Qs[(jj * 256 + tid) * 8] = qv[jj];
      *(bf16x8*)&Ks[(jj * 256 + tid) * 8] = kv[jj];
    }
    __syncthreads();
    bf16x8 qf[3], kf[3];
#pragma unroll
    for (int i = 0; i < 3; i++) {
      qf[i] = *(const bf16x8*)&Qs[wave * 1536 + (i * 16 + l16) * 32 + q4 * 8];
      kf[i] = *(const bf16x8*)&Ks[wave * 1536 + (i * 16 + l16) * 32 + q4 * 8];
    }
#pragma unroll
    for (int i = 0; i < 3; i++) {
#pragma unroll
      for (int u = 0; u < 8; u++) {
        const float qv2 = (float)qf[i][u], kv2 = (float)kf[i][u];
        qss[i] += qv2 * qv2;
        kss[i] += kv2 * kv2;
      }
#pragma unroll
      for (int j = 0; j < 3; j++) acc[i][j] = mfma16(qf[i], kf[j], acc[i][j]);
    }
  }

  __syncthreads();
  float* red = sm;  // 4 waves x 2304 fp32
#pragma unroll
  for (int i = 0; i < 3; i++)
#pragma unroll
    for (int j = 0; j < 3; j++)
#pragma unroll
      for (int r = 0; r < 4; r++)
        red[wave * 2304 + (i * 3 + j) * 256 + lane * 4 + r] = acc[i][j][r];
#pragma unroll
  for (int i = 0; i < 3; i++) {
    atomicAdd(&ssq_sm[i * 16 + l16], qss[i]);
    atomicAdd(&ssq_sm[48 + i * 16 + l16], kss[i]);
  }
  __syncthreads();
  for (int idx = tid; idx < 2304; idx += 256) {
    const float v = red[idx] + red[2304 + idx] + red[4608 + idx] + red[6912 + idx];
    const int tile = idx >> 8, ln = (idx >> 2) & 63, r = idx & 3;
    const int i = tile / 3, j = tile - i * 3;
    const int d = i * 16 + ((ln >> 4) << 2) + r;
    const int e = j * 16 + (ln & 15);
    atomicAdd(&S_acc[bh * 2304 + d * 48 + e], v);
  }
  if (tid < 96) atomicAdd(&ssq_acc[bh * 96 + tid], ssq_sm[tid]);
}

// ---------------- K3: softmax(S / (|q_d||k_e|)) ----------------
__global__ void k_softmax(const float* __restrict__ S_acc, const float* __restrict__ ssq_acc,
                          float* __restrict__ attn_f) {
  __shared__ float invk_sm[48];
  const int bh = blockIdx.x, d = threadIdx.x;
  if (d < 48) invk_sm[d] = 1.f / fmaxf(sqrtf(ssq_acc[bh * 96 + 48 + d]), 1e-12f);
  __syncthreads();
  if (d < 48) {
    const float invq = 1.f / fmaxf(sqrtf(ssq_acc[bh * 96 + d]), 1e-12f);
    float lg[48], mx = -1e30f;
#pragma unroll
    for (int e = 0; e < 48; e++) {
      lg[e] = S_acc[bh * 2304 + d * 48 + e] * invq * invk_sm[e];
      mx = fmaxf(mx, lg[e]);
    }
    float ssum = 0.f;
#pragma unroll
    for (int e = 0; e < 48; e++) { lg[e] = expf(lg[e] - mx); ssum += lg[e]; }
    const float inv = 1.f / ssum;
#pragma unroll
    for (int e = 0; e < 48; e++) attn_f[bh * 2304 + d * 48 + e] = lg[e] * inv;
  }
}

// ---------------- K4: Weff_b[c'][h*48+e] = sum_d Wp[c'][h*48+d] attn[bh][d][e] ------
__global__ void k_weff(
    const float* __restrict__ attn_f, const void* __restrict__ Wp,
    bf16_t* __restrict__ Weff, const int* __restrict__ flagp) {
  __shared__ float attn_sm[2304];
  const int isb = *flagp;
  const int b = blockIdx.x >> 3, h = blockIdx.x & 7;
  const int tid = threadIdx.x, bh = b * 8 + h;
  for (int i = tid; i < 2304; i += 256) attn_sm[i] = attn_f[bh * 2304 + i];
  __syncthreads();
  const int cb = tid >> 3, eb = tid & 7;
  float res[12][6];
#pragma unroll
  for (int u = 0; u < 12; u++)
#pragma unroll
    for (int v = 0; v < 6; v++) res[u][v] = 0.f;

  for (int d8 = 0; d8 < 6; d8++) {
    bf16x8 wv[12];
#pragma unroll
    for (int u = 0; u < 12; u++) {
      const int idx = (cb * 12 + u) * CDIM + h * 48 + d8 * 8;
      wv[u] = isb ? load8<true>(Wp, idx) : load8<false>(Wp, idx);
    }
#pragma unroll
    for (int dd = 0; dd < 8; dd++) {
      float wf[12];
#pragma unroll
      for (int u = 0; u < 12; u++) wf[u] = (float)wv[u][dd];
      const int d = d8 * 8 + dd;
#pragma unroll
      for (int v = 0; v < 6; v++) {
        const float a = attn_sm[d * 48 + eb * 6 + v];
#pragma unroll
        for (int u = 0; u < 12; u++) res[u][v] += wf[u] * a;
      }
    }
  }
#pragma unroll
  for (int u = 0; u < 12; u++)
#pragma unroll
    for (int v = 0; v < 6; v++)
      Weff[b * 147456 + (cb * 12 + u) * CDIM + h * 48 + eb * 6 + v] = (bf16_t)res[u][v];
}

// ---------------- K5: out[b,n,c'] = sum_c Weff_b[c'][c] V[b,n,c] + bias[c'] --------
// Grid (64 nt, 8 b); ct=0..2 INSIDE (R0 schedule: V-tile L2-resident across
// the 3 c'-tiles; 2 blocks/CU).
__global__ __launch_bounds__(256, 2) void k_gemm_out(
    const bf16_t* __restrict__ Weff, const bf16_t* __restrict__ qkv,
    const void* __restrict__ bias, void* __restrict__ out, const int* __restrict__ flagp) {
  __shared__ __align__(16) bf16_t As[128 * 32];
  __shared__ __align__(16) bf16_t Bs[128 * 32];
  const int isb = *flagp;
  const int tid = threadIdx.x;
  const int lane = tid & 63;
  const int wr = tid >> 7, wc = (tid >> 6) & 1;
  const int q4 = lane >> 4, l16 = lane & 15;
  const int b = blockIdx.y;
  const int rowB0 = blockIdx.x * 128;  // n tile
  const bf16_t* Aa = Weff + b * 147456;
  const bf16_t* Ba = qkv + 2 * WH + b * (NTOK * CDIM);
  const int r0 = tid >> 2, kk = (tid & 3) << 3;

  for (int ct = 0; ct < 3; ct++) {
    const int rowA0 = ct * 128;
    f32x4 acc[4][4];
#pragma unroll
    for (int i = 0; i < 4; i++)
#pragma unroll
      for (int j = 0; j < 4; j++) acc[i][j] = (f32x4){0.f, 0.f, 0.f, 0.f};

    for (int k0 = 0; k0 < CDIM; k0 += 32) {
      bf16x8 a0 = *(const bf16x8*)(Aa + (rowA0 + r0) * CDIM + k0 + kk);
      bf16x8 a1 = *(const bf16x8*)(Aa + (rowA0 + r0 + 64) * CDIM + k0 + kk);
      bf16x8 b0 = *(const bf16x8*)(Ba + (rowB0 + r0) * CDIM + k0 + kk);
      bf16x8 b1 = *(const bf16x8*)(Ba + (rowB0 + r0 + 64) * CDIM + k0 + kk);
      __syncthreads();
      *(bf16x8*)&As[tid * 8] = a0;
      *(bf16x8*)&As[(tid + 256) * 8] = a1;
      *(bf16x8*)&Bs[tid * 8] = b0;
      *(bf16x8*)&Bs[(tid + 256) * 8] = b1;
      __syncthreads();
      bf16x8 af[4], bfr[4];
#pragma unroll
      for (int i = 0; i < 4; i++) {
        af[i]  = *(const bf16x8*)&As[(wr * 64 + i * 16 + l16) * 32 + q4 * 8];
        bfr[i] = *(const bf16x8*)&Bs[(wc * 64 + i * 16 + l16) * 32 + q4 * 8];
      }
#pragma unroll
      for (int i = 0; i < 4; i++)
#pragma unroll
        for (int j = 0; j < 4; j++) acc[i][j] = mfma16(af[i], bfr[j], acc[i][j]);
    }

#pragma unroll
    for (int i = 0; i < 4; i++) {
      const int cg = rowA0 + wr * 64 + i * 16 + q4 * 4;
      float bv[4];
#pragma unroll
      for (int r = 0; r < 4; r++)
        bv[r] = isb ? (float)((const bf16_t*)bias)[cg + r] : ((const float*)bias)[cg + r];
#pragma unroll
      for (int j = 0; j < 4; j++) {
        const int ng = rowB0 + wc * 64 + j * 16 + l16;
        const int oi = (b * NTOK + ng) * CDIM + cg;
        if (isb) {
          bf16x4 o = {(bf16_t)(acc[i][j][0] + bv[0]), (bf16_t)(acc[i][j][1] + bv[1]),
                      (bf16_t)(acc[i][j][2] + bv[2]), (bf16_t)(acc[i][j][3] + bv[3])};
          *(bf16x4*)((bf16_t*)out + oi) = o;
        } else {
          f32x4 o = {acc[i][j][0] + bv[0], acc[i][j][1] + bv[1],
                     acc[i][j][2] + bv[2], acc[i][j][3] + bv[3]};
          *(f32x4*)((float*)out + oi) = o;
        }
      }
    }
  }
}

extern "C" void kernel_launch(void* const* d_in, const int* in_sizes, int n_in,
                              void* d_out, int out_size, void* d_ws, size_t ws_size,
                              hipStream_t stream) {
  (void)in_sizes; (void)n_in; (void)out_size;
  const void* X    = d_in[0];
  const void* Wqkv = d_in[1];
  const void* Wp   = d_in[2];
  const void* bias = d_in[3];

  char* ws = (char*)d_ws;
  bf16_t* qkv    = (bf16_t*)ws;                     // 3*WH bf16 = 150,994,944 B
  float*  S_acc  = (float*)(ws + 150994944);        // 64*2304 f32
  float*  ssq    = (float*)(ws + 151584768);        // 64*96 f32
  float*  attn_f = (float*)(ws + 151609344);        // 64*2304 f32
  bf16_t* Weff   = (bf16_t*)(ws + 152199168);       // 8*384*384 bf16
  int*    flag   = (int*)(ws + 154558464);
  bf16_t* Xb     = (bf16_t*)(ws + 154558720);       // 50,331,648 B
  bf16_t* Wb     = (bf16_t*)(ws + 204890368);       // 884,736 B -> end 205,775,104

  const bool have_cvt_ws = ws_size >= 205775104ULL;

  k_probe<<<dim3(1), 256, 0, stream>>>((const uint32_t*)X, flag);
  k_zero<<<dim3(600), 256, 0, stream>>>(S_acc, 153600);
  if (have_cvt_ws) {
    k_cvt<<<dim3(2048), 256, 0, stream>>>(X, Wqkv, Xb, Wb, flag);
    k_gemm_qkv<<<dim3(512), 256, 0, stream>>>(Xb, Wb, qkv);
  } else {
    k_gemm_qkv_bf16<<<dim3(512), 256, 0, stream>>>(X, Wqkv, qkv, flag);
    k_gemm_qkv_f32<<<dim3(512), 256, 0, stream>>>(X, Wqkv, qkv, flag);
  }
  k_gram<<<dim3(8, 64), 256, 0, stream>>>(qkv, S_acc, ssq);
  k_softmax<<<dim3(64), 64, 0, stream>>>(S_acc, ssq, attn_f);
  k_weff<<<dim3(64), 256, 0, stream>>>(attn_f, Wp, Weff, flag);
  k_gemm_out<<<dim3(64, 8), 256, 0, stream>>>(Weff, qkv, bias, d_out, flag);
}

// Round 7
// 407.315 us; speedup vs baseline: 2.4406x; 1.2196x over previous
//
#include <hip/hip_runtime.h>
#include <hip/hip_bf16.h>
#include <stdint.h>

// XCA (cross-covariance attention), B=8 N=8192 C=384 H=8 Dh=48.
// R10: R9 counters show k_weff = 162us, the new #1 kernel. Cause: without
// launch_bounds the compiler allocated VGPR=64 vs ~140 live (res[12][6]+
// wv[12]) -> res[] in scratch -> ~3456 latency-serialized scratch RMW per
// thread (VALUBusy 0.013%). Fix: restructure k_weff to be register-tiny:
// per block = (b, h, c'-tile of 48); stage 48x48 attn AND 48x48 Wp tiles in
// LDS (18KB); each thread computes 9 outputs with an LDS-only dot loop
// (1 scalar acc). Grid 512. Also upgrades f32-path precision (no more
// Wp->bf16 rounding in K4).
// Everything else identical to R9 (k_gemm_qkv: jt-inside, 2 blocks/CU,
// reg-staging, 127us, FETCH 50MB / WRITE 162MB exact).

typedef __bf16 bf16_t;
typedef __attribute__((ext_vector_type(8))) __bf16 bf16x8;
typedef __attribute__((ext_vector_type(4))) __bf16 bf16x4;
typedef __attribute__((ext_vector_type(4))) float f32x4;

#define NTOK 8192
#define CDIM 384
#define WH   25165824   // 8*8*48*8192 elements per q/k plane
#define DHN  393216     // 48*8192

#define XCHUNKS 3145728   // 25,165,824 X elems / 8
#define TCHUNKS 3201024   // + 442,368 W elems / 8

__device__ __forceinline__ f32x4 mfma16(bf16x8 a, bf16x8 b, f32x4 c) {
  return __builtin_amdgcn_mfma_f32_16x16x32_bf16(a, b, c, 0, 0, 0);
}

template <bool BF16>
__device__ __forceinline__ bf16x8 load8(const void* p, int idx) {
  if constexpr (BF16) {
    return *(const bf16x8*)((const bf16_t*)p + idx);
  } else {
    const float* f = (const float*)p + idx;
    f32x4 a = *(const f32x4*)f;
    f32x4 b = *(const f32x4*)(f + 4);
    bf16x8 r;
    r[0] = (bf16_t)a[0]; r[1] = (bf16_t)a[1]; r[2] = (bf16_t)a[2]; r[3] = (bf16_t)a[3];
    r[4] = (bf16_t)b[0]; r[5] = (bf16_t)b[1]; r[6] = (bf16_t)b[2]; r[7] = (bf16_t)b[3];
    return r;
  }
}

// ---------------- probe: are inputs bf16 (1) or f32 (0)? ----------------
__global__ void k_probe(const uint32_t* __restrict__ X, int* __restrict__ flag) {
  __shared__ int cnt;
  if (threadIdx.x == 0) cnt = 0;
  __syncthreads();
  const uint32_t w = X[threadIdx.x];
  const int e = (int)((w >> 7) & 0xFF);  // exponent of low-16 as bf16
  const int sane = (e >= 110 && e <= 131) ? 1 : 0;
  atomicAdd(&cnt, sane);
  __syncthreads();
  if (threadIdx.x == 0) *flag = (cnt >= 128) ? 1 : 0;
}

// ---------------- zero fp32 accumulators ----------------
__global__ void k_zero(float* __restrict__ p, int n) {
  int i = blockIdx.x * 256 + threadIdx.x;
  if (i < n) p[i] = 0.f;
}

// ---------------- cvt: X,Wqkv (f32 or bf16) -> bf16 workspace ----------------
__global__ void k_cvt(const void* __restrict__ X, const void* __restrict__ Wqkv,
                      bf16_t* __restrict__ Xb, bf16_t* __restrict__ Wb,
                      const int* __restrict__ flagp) {
  const int isb = *flagp;
  const int G = gridDim.x * 256;
  for (int c = blockIdx.x * 256 + threadIdx.x; c < TCHUNKS; c += G) {
    const bool isX = c < XCHUNKS;
    const int lc = isX ? c : c - XCHUNKS;          // chunk within its buffer
    const void* src = isX ? X : Wqkv;
    bf16_t* dst = (isX ? Xb : Wb) + (size_t)lc * 8;
    if (isb) {
      *(bf16x8*)dst = *((const bf16x8*)src + lc);
    } else {
      const f32x4 a = *((const f32x4*)src + lc * 2);
      const f32x4 b = *((const f32x4*)src + lc * 2 + 1);
      bf16x8 r;
      r[0] = (bf16_t)a[0]; r[1] = (bf16_t)a[1]; r[2] = (bf16_t)a[2]; r[3] = (bf16_t)a[3];
      r[4] = (bf16_t)b[0]; r[5] = (bf16_t)b[1]; r[6] = (bf16_t)b[2]; r[7] = (bf16_t)b[3];
      *(bf16x8*)dst = r;
    }
  }
}

// ---------------- K1: qkv = x @ w_qkv^T ----------------
// Grid (512). jt=0..8 INSIDE the block (R0 schedule): the 98 KB x-tile stays
// L2-resident across all 9 A-tiles; 2 blocks/CU keeps the cache hierarchy
// absorbing the re-reads (R9: 50 MB FETCH vs 885 MB issued).
// q/k tiles (which<2): swapped MFMA (D row = token) -> bf16x4 stores along N.
// v tiles: original order (D row = channel) -> bf16x4 stores along C.
template <bool BF16>
__device__ __forceinline__ void qkv_body(const void* __restrict__ X,
                                         const void* __restrict__ Wqkv,
                                         bf16_t* __restrict__ qkv,
                                         bf16_t* As, bf16_t* Bs) {
  const int tid = threadIdx.x;
  const int lane = tid & 63;
  const int wr = tid >> 7, wc = (tid >> 6) & 1;
  const int q4 = lane >> 4, l16 = lane & 15;
  const int rowB0 = blockIdx.x * 128;
  const int r0 = tid >> 2, kk = (tid & 3) << 3;
  const int bb = rowB0 >> 13;       // batch index (tiles never cross b)
  const int nB = rowB0 & 8191;      // token base within batch

  for (int jt = 0; jt < 9; jt++) {
    const int rowA0 = jt * 128;
    const int which = jt / 3;       // 0=q 1=k 2=v (uniform per jt)
    const int jtt = jt - which * 3;
    f32x4 acc[4][4];
#pragma unroll
    for (int i = 0; i < 4; i++)
#pragma unroll
      for (int j = 0; j < 4; j++) acc[i][j] = (f32x4){0.f, 0.f, 0.f, 0.f};

    for (int k0 = 0; k0 < CDIM; k0 += 32) {
      bf16x8 a0 = load8<BF16>(Wqkv, (rowA0 + r0) * CDIM + k0 + kk);
      bf16x8 a1 = load8<BF16>(Wqkv, (rowA0 + r0 + 64) * CDIM + k0 + kk);
      bf16x8 b0 = load8<BF16>(X, (rowB0 + r0) * CDIM + k0 + kk);
      bf16x8 b1 = load8<BF16>(X, (rowB0 + r0 + 64) * CDIM + k0 + kk);
      __syncthreads();  // prior iteration's LDS frag reads complete
      *(bf16x8*)&As[tid * 8] = a0;
      *(bf16x8*)&As[(tid + 256) * 8] = a1;
      *(bf16x8*)&Bs[tid * 8] = b0;
      *(bf16x8*)&Bs[(tid + 256) * 8] = b1;
      __syncthreads();
      bf16x8 af[4], bfr[4];
#pragma unroll
      for (int i = 0; i < 4; i++) {
        af[i]  = *(const bf16x8*)&As[(wr * 64 + i * 16 + l16) * 32 + q4 * 8];
        bfr[i] = *(const bf16x8*)&Bs[(wc * 64 + i * 16 + l16) * 32 + q4 * 8];
      }
      if (which < 2) {
#pragma unroll
        for (int i = 0; i < 4; i++)
#pragma unroll
          for (int j = 0; j < 4; j++) acc[i][j] = mfma16(bfr[j], af[i], acc[i][j]);
      } else {
#pragma unroll
        for (int i = 0; i < 4; i++)
#pragma unroll
          for (int j = 0; j < 4; j++) acc[i][j] = mfma16(af[i], bfr[j], acc[i][j]);
      }
    }

    if (which < 2) {
      // swapped: acc[i][j][r] = D[token = rowB0+wc*64+j*16+q4*4+r][ch = rowA0+wr*64+i*16+l16]
#pragma unroll
      for (int i = 0; i < 4; i++) {
        const int rin = jtt * 128 + wr * 64 + i * 16 + l16;  // channel within plane
        const int h = rin / 48, dh = rin - h * 48;
        bf16_t* rowp = qkv + which * WH + (bb * 8 + h) * DHN + dh * NTOK
                       + nB + wc * 64 + q4 * 4;
#pragma unroll
        for (int j = 0; j < 4; j++) {
          bf16x4 o = {(bf16_t)acc[i][j][0], (bf16_t)acc[i][j][1],
                      (bf16_t)acc[i][j][2], (bf16_t)acc[i][j][3]};
          *(bf16x4*)(rowp + j * 16) = o;
        }
      }
    } else {
      // original: acc[i][j][r] = D[ch = rowA0+wr*64+i*16+q4*4+r][token = rowB0+wc*64+j*16+l16]
#pragma unroll
      for (int i = 0; i < 4; i++) {
        const int rin0 = jtt * 128 + wr * 64 + i * 16 + q4 * 4;  // c within v
#pragma unroll
        for (int j = 0; j < 4; j++) {
          const int mg = rowB0 + wc * 64 + j * 16 + l16;
          bf16x4 o = {(bf16_t)acc[i][j][0], (bf16_t)acc[i][j][1],
                      (bf16_t)acc[i][j][2], (bf16_t)acc[i][j][3]};
          *(bf16x4*)(qkv + 2 * WH + mg * CDIM + rin0) = o;
        }
      }
    }
  }
}

// main path: inputs already bf16 in workspace. bounds(256,2) proven safe
// (R9 VGPR=128 no spill) and caps concurrency at 2 blocks/CU for absorption.
__global__ __launch_bounds__(256, 2) void k_gemm_qkv(
    const bf16_t* __restrict__ Xb, const bf16_t* __restrict__ Wb,
    bf16_t* __restrict__ qkv) {
  __shared__ __align__(16) bf16_t As[128 * 32];
  __shared__ __align__(16) bf16_t Bs[128 * 32];
  qkv_body<true>(Xb, Wb, qkv, As, Bs);
}

// fallback path (ws too small for cvt buffers): flag-gated pair on raw inputs.
__global__ __launch_bounds__(256, 2) void k_gemm_qkv_bf16(
    const void* __restrict__ X, const void* __restrict__ Wqkv,
    bf16_t* __restrict__ qkv, const int* __restrict__ flagp) {
  __shared__ __align__(16) bf16_t As[128 * 32];
  __shared__ __align__(16) bf16_t Bs[128 * 32];
  if (!*flagp) return;
  qkv_body<true>(X, Wqkv, qkv, As, Bs);
}

__global__ __launch_bounds__(256, 2) void k_gemm_qkv_f32(
    const void* __restrict__ X, const void* __restrict__ Wqkv,
    bf16_t* __restrict__ qkv, const int* __restrict__ flagp) {
  __shared__ __align__(16) bf16_t As[128 * 32];
  __shared__ __align__(16) bf16_t Bs[128 * 32];
  if (*flagp) return;
  qkv_body<false>(X, Wqkv, qkv, As, Bs);
}

// ---------------- K2: Gram S=Q K^T + sumsq ----------------
__global__ __launch_bounds__(256, 2) void k_gram(
    const bf16_t* __restrict__ qkv, float* __restrict__ S_acc, float* __restrict__ ssq_acc) {
  __shared__ __align__(16) float sm[9312];  // 37,248 B
  bf16_t* Qs = (bf16_t*)sm;                 // 6144 bf16 = [4][48][32]
  bf16_t* Ks = Qs + 6144;
  float* ssq_sm = sm + 9216;                // 96 floats

  const int tid = threadIdx.x;
  const int wave = tid >> 6, lane = tid & 63, q4 = lane >> 4, l16 = lane & 15;
  const int s = blockIdx.x, bh = blockIdx.y;
  const bf16_t* Qg = qkv + bh * DHN;
  const bf16_t* Kg = qkv + WH + bh * DHN;

  if (tid < 96) ssq_sm[tid] = 0.f;

  f32x4 acc[3][3];
#pragma unroll
  for (int i = 0; i < 3; i++)
#pragma unroll
    for (int j = 0; j < 3; j++) acc[i][j] = (f32x4){0.f, 0.f, 0.f, 0.f};
  float qss[3] = {0.f, 0.f, 0.f}, kss[3] = {0.f, 0.f, 0.f};

  for (int t0 = 0; t0 < 8; t0++) {
    const int n0 = s * 1024 + t0 * 128;
    bf16x8 qv[3], kv[3];
#pragma unroll
    for (int jj = 0; jj < 3; jj++) {
      const int c = jj * 256 + tid;
      const int st = c / 192, rem = c - st * 192;
      const int row = rem >> 2, kk = (rem & 3) << 3;
      const int gofs = row * NTOK + n0 + st * 32 + kk;
      qv[jj] = *(const bf16x8*)(Qg + gofs);
      kv[jj] = *(const bf16x8*)(Kg + gofs);
    }
    __syncthreads();
#pragma unroll
    for (int jj = 0; jj < 3; jj++) {
      *(bf16x8*)&Qs[(jj * 256 + tid) * 8] = qv[jj];
      *(bf16x8*)&Ks[(jj * 256 + tid) * 8] = kv[jj];
    }
    __syncthreads();
    bf16x8 qf[3], kf[3];
#pragma unroll
    for (int i = 0; i < 3; i++) {
      qf[i] = *(const bf16x8*)&Qs[wave * 1536 + (i * 16 + l16) * 32 + q4 * 8];
      kf[i] = *(const bf16x8*)&Ks[wave * 1536 + (i * 16 + l16) * 32 + q4 * 8];
    }
#pragma unroll
    for (int i = 0; i < 3; i++) {
#pragma unroll
      for (int u = 0; u < 8; u++) {
        const float qv2 = (float)qf[i][u], kv2 = (float)kf[i][u];
        qss[i] += qv2 * qv2;
        kss[i] += kv2 * kv2;
      }
#pragma unroll
      for (int j = 0; j < 3; j++) acc[i][j] = mfma16(qf[i], kf[j], acc[i][j]);
    }
  }

  __syncthreads();
  float* red = sm;  // 4 waves x 2304 fp32
#pragma unroll
  for (int i = 0; i < 3; i++)
#pragma unroll
    for (int j = 0; j < 3; j++)
#pragma unroll
      for (int r = 0; r < 4; r++)
        red[wave * 2304 + (i * 3 + j) * 256 + lane * 4 + r] = acc[i][j][r];
#pragma unroll
  for (int i = 0; i < 3; i++) {
    atomicAdd(&ssq_sm[i * 16 + l16], qss[i]);
    atomicAdd(&ssq_sm[48 + i * 16 + l16], kss[i]);
  }
  __syncthreads();
  for (int idx = tid; idx < 2304; idx += 256) {
    const float v = red[idx] + red[2304 + idx] + red[4608 + idx] + red[6912 + idx];
    const int tile = idx >> 8, ln = (idx >> 2) & 63, r = idx & 3;
    const int i = tile / 3, j = tile - i * 3;
    const int d = i * 16 + ((ln >> 4) << 2) + r;
    const int e = j * 16 + (ln & 15);
    atomicAdd(&S_acc[bh * 2304 + d * 48 + e], v);
  }
  if (tid < 96) atomicAdd(&ssq_acc[bh * 96 + tid], ssq_sm[tid]);
}

// ---------------- K3: softmax(S / (|q_d||k_e|)) ----------------
__global__ void k_softmax(const float* __restrict__ S_acc, const float* __restrict__ ssq_acc,
                          float* __restrict__ attn_f) {
  __shared__ float invk_sm[48];
  const int bh = blockIdx.x, d = threadIdx.x;
  if (d < 48) invk_sm[d] = 1.f / fmaxf(sqrtf(ssq_acc[bh * 96 + 48 + d]), 1e-12f);
  __syncthreads();
  if (d < 48) {
    const float invq = 1.f / fmaxf(sqrtf(ssq_acc[bh * 96 + d]), 1e-12f);
    float lg[48], mx = -1e30f;
#pragma unroll
    for (int e = 0; e < 48; e++) {
      lg[e] = S_acc[bh * 2304 + d * 48 + e] * invq * invk_sm[e];
      mx = fmaxf(mx, lg[e]);
    }
    float ssum = 0.f;
#pragma unroll
    for (int e = 0; e < 48; e++) { lg[e] = expf(lg[e] - mx); ssum += lg[e]; }
    const float inv = 1.f / ssum;
#pragma unroll
    for (int e = 0; e < 48; e++) attn_f[bh * 2304 + d * 48 + e] = lg[e] * inv;
  }
}

// ---------------- K4: Weff_b[c'][h*48+e] = sum_d Wp[c'][h*48+d] attn[bh][d][e] ------
// R10 rewrite: register-tiny LDS-tile formulation. Block = (b, h, ct) where
// ct indexes a 48-row c' tile. Stage attn 48x48 and Wp 48x48 in LDS; each
// thread computes 9 outputs with a scalar accumulator (no big reg arrays ->
// no scratch regardless of allocator heuristics).
__global__ void k_weff(
    const float* __restrict__ attn_f, const void* __restrict__ Wp,
    bf16_t* __restrict__ Weff, const int* __restrict__ flagp) {
  __shared__ float a_sm[2304];  // attn[d][e]
  __shared__ float w_sm[2304];  // Wp[c'_local][d]
  const int isb = *flagp;
  const int bid = blockIdx.x;
  const int ct = bid & 7, h = (bid >> 3) & 7, b = bid >> 6;
  const int bh = b * 8 + h;
  const int tid = threadIdx.x;

  for (int i = tid; i < 2304; i += 256) {
    a_sm[i] = attn_f[bh * 2304 + i];
    const int r = i / 48, c = i - r * 48;
    const int gi = (ct * 48 + r) * CDIM + h * 48 + c;
    w_sm[i] = isb ? (float)((const bf16_t*)Wp)[gi] : ((const float*)Wp)[gi];
  }
  __syncthreads();

  for (int o = tid; o < 2304; o += 256) {
    const int r = o / 48, e = o - r * 48;
    float s = 0.f;
#pragma unroll 8
    for (int d = 0; d < 48; d++) s += w_sm[r * 48 + d] * a_sm[d * 48 + e];
    Weff[b * 147456 + (ct * 48 + r) * CDIM + h * 48 + e] = (bf16_t)s;
  }
}

// ---------------- K5: out[b,n,c'] = sum_c Weff_b[c'][c] V[b,n,c] + bias[c'] --------
// Grid (64 nt, 8 b); ct=0..2 INSIDE (R0 schedule: V-tile L2-resident across
// the 3 c'-tiles; 2 blocks/CU).
__global__ __launch_bounds__(256, 2) void k_gemm_out(
    const bf16_t* __restrict__ Weff, const bf16_t* __restrict__ qkv,
    const void* __restrict__ bias, void* __restrict__ out, const int* __restrict__ flagp) {
  __shared__ __align__(16) bf16_t As[128 * 32];
  __shared__ __align__(16) bf16_t Bs[128 * 32];
  const int isb = *flagp;
  const int tid = threadIdx.x;
  const int lane = tid & 63;
  const int wr = tid >> 7, wc = (tid >> 6) & 1;
  const int q4 = lane >> 4, l16 = lane & 15;
  const int b = blockIdx.y;
  const int rowB0 = blockIdx.x * 128;  // n tile
  const bf16_t* Aa = Weff + b * 147456;
  const bf16_t* Ba = qkv + 2 * WH + b * (NTOK * CDIM);
  const int r0 = tid >> 2, kk = (tid & 3) << 3;

  for (int ct = 0; ct < 3; ct++) {
    const int rowA0 = ct * 128;
    f32x4 acc[4][4];
#pragma unroll
    for (int i = 0; i < 4; i++)
#pragma unroll
      for (int j = 0; j < 4; j++) acc[i][j] = (f32x4){0.f, 0.f, 0.f, 0.f};

    for (int k0 = 0; k0 < CDIM; k0 += 32) {
      bf16x8 a0 = *(const bf16x8*)(Aa + (rowA0 + r0) * CDIM + k0 + kk);
      bf16x8 a1 = *(const bf16x8*)(Aa + (rowA0 + r0 + 64) * CDIM + k0 + kk);
      bf16x8 b0 = *(const bf16x8*)(Ba + (rowB0 + r0) * CDIM + k0 + kk);
      bf16x8 b1 = *(const bf16x8*)(Ba + (rowB0 + r0 + 64) * CDIM + k0 + kk);
      __syncthreads();
      *(bf16x8*)&As[tid * 8] = a0;
      *(bf16x8*)&As[(tid + 256) * 8] = a1;
      *(bf16x8*)&Bs[tid * 8] = b0;
      *(bf16x8*)&Bs[(tid + 256) * 8] = b1;
      __syncthreads();
      bf16x8 af[4], bfr[4];
#pragma unroll
      for (int i = 0; i < 4; i++) {
        af[i]  = *(const bf16x8*)&As[(wr * 64 + i * 16 + l16) * 32 + q4 * 8];
        bfr[i] = *(const bf16x8*)&Bs[(wc * 64 + i * 16 + l16) * 32 + q4 * 8];
      }
#pragma unroll
      for (int i = 0; i < 4; i++)
#pragma unroll
        for (int j = 0; j < 4; j++) acc[i][j] = mfma16(af[i], bfr[j], acc[i][j]);
    }

#pragma unroll
    for (int i = 0; i < 4; i++) {
      const int cg = rowA0 + wr * 64 + i * 16 + q4 * 4;
      float bv[4];
#pragma unroll
      for (int r = 0; r < 4; r++)
        bv[r] = isb ? (float)((const bf16_t*)bias)[cg + r] : ((const float*)bias)[cg + r];
#pragma unroll
      for (int j = 0; j < 4; j++) {
        const int ng = rowB0 + wc * 64 + j * 16 + l16;
        const int oi = (b * NTOK + ng) * CDIM + cg;
        if (isb) {
          bf16x4 o = {(bf16_t)(acc[i][j][0] + bv[0]), (bf16_t)(acc[i][j][1] + bv[1]),
                      (bf16_t)(acc[i][j][2] + bv[2]), (bf16_t)(acc[i][j][3] + bv[3])};
          *(bf16x4*)((bf16_t*)out + oi) = o;
        } else {
          f32x4 o = {acc[i][j][0] + bv[0], acc[i][j][1] + bv[1],
                     acc[i][j][2] + bv[2], acc[i][j][3] + bv[3]};
          *(f32x4*)((float*)out + oi) = o;
        }
      }
    }
  }
}

extern "C" void kernel_launch(void* const* d_in, const int* in_sizes, int n_in,
                              void* d_out, int out_size, void* d_ws, size_t ws_size,
                              hipStream_t stream) {
  (void)in_sizes; (void)n_in; (void)out_size;
  const void* X    = d_in[0];
  const void* Wqkv = d_in[1];
  const void* Wp   = d_in[2];
  const void* bias = d_in[3];

  char* ws = (char*)d_ws;
  bf16_t* qkv    = (bf16_t*)ws;                     // 3*WH bf16 = 150,994,944 B
  float*  S_acc  = (float*)(ws + 150994944);        // 64*2304 f32
  float*  ssq    = (float*)(ws + 151584768);        // 64*96 f32
  float*  attn_f = (float*)(ws + 151609344);        // 64*2304 f32
  bf16_t* Weff   = (bf16_t*)(ws + 152199168);       // 8*384*384 bf16
  int*    flag   = (int*)(ws + 154558464);
  bf16_t* Xb     = (bf16_t*)(ws + 154558720);       // 50,331,648 B
  bf16_t* Wb     = (bf16_t*)(ws + 204890368);       // 884,736 B -> end 205,775,104

  const bool have_cvt_ws = ws_size >= 205775104ULL;

  k_probe<<<dim3(1), 256, 0, stream>>>((const uint32_t*)X, flag);
  k_zero<<<dim3(600), 256, 0, stream>>>(S_acc, 153600);
  if (have_cvt_ws) {
    k_cvt<<<dim3(2048), 256, 0, stream>>>(X, Wqkv, Xb, Wb, flag);
    k_gemm_qkv<<<dim3(512), 256, 0, stream>>>(Xb, Wb, qkv);
  } else {
    k_gemm_qkv_bf16<<<dim3(512), 256, 0, stream>>>(X, Wqkv, qkv, flag);
    k_gemm_qkv_f32<<<dim3(512), 256, 0, stream>>>(X, Wqkv, qkv, flag);
  }
  k_gram<<<dim3(8, 64), 256, 0, stream>>>(qkv, S_acc, ssq);
  k_softmax<<<dim3(64), 64, 0, stream>>>(S_acc, ssq, attn_f);
  k_weff<<<dim3(512), 256, 0, stream>>>(attn_f, Wp, Weff, flag);
  k_gemm_out<<<dim3(64, 8), 256, 0, stream>>>(Weff, qkv, bias, d_out, flag);
}

// Round 8
// 407.059 us; speedup vs baseline: 2.4421x; 1.0006x over previous
//
#include <hip/hip_runtime.h>
#include <hip/hip_bf16.h>
#include <stdint.h>

// XCA (cross-covariance attention), B=8 N=8192 C=384 H=8 Dh=48.
// R11: R10 confirmed (407us; k_weff fixed). k_gemm_qkv (133us) is 4-5x above
// roofs, latency-bound in the staging chain (MfmaUtil 17.5%, VALUBusy 6.4%).
// Change ONE variable: staging path reg->global_load_lds in k_gemm_qkv main
// path + k_gemm_out, at the PROVEN schedule (jt/ct-inside, 2 blocks/CU).
// R5's traffic blowup was concurrency (R8: reg-staging at 4-8 blocks/CU blew
// up identically), not gload_lds; m151 measured +35% for gload_lds at this
// tile size. If FETCH/WRITE stay ~50/162MB the concurrency theory holds and
// we pocket the latency win.

typedef __bf16 bf16_t;
typedef __attribute__((ext_vector_type(8))) __bf16 bf16x8;
typedef __attribute__((ext_vector_type(4))) __bf16 bf16x4;
typedef __attribute__((ext_vector_type(4))) float f32x4;

#define NTOK 8192
#define CDIM 384
#define WH   25165824   // 8*8*48*8192 elements per q/k plane
#define DHN  393216     // 48*8192

#define XCHUNKS 3145728   // 25,165,824 X elems / 8
#define TCHUNKS 3201024   // + 442,368 W elems / 8

__device__ __forceinline__ f32x4 mfma16(bf16x8 a, bf16x8 b, f32x4 c) {
  return __builtin_amdgcn_mfma_f32_16x16x32_bf16(a, b, c, 0, 0, 0);
}

// async global->LDS, 16B per lane (wave-uniform base + lane*16 idiom).
__device__ __forceinline__ void gload16(bf16_t* lds, const bf16_t* g) {
  __builtin_amdgcn_global_load_lds(
      (const __attribute__((address_space(1))) void*)g,
      (__attribute__((address_space(3))) void*)lds, 16, 0, 0);
}

template <bool BF16>
__device__ __forceinline__ bf16x8 load8(const void* p, int idx) {
  if constexpr (BF16) {
    return *(const bf16x8*)((const bf16_t*)p + idx);
  } else {
    const float* f = (const float*)p + idx;
    f32x4 a = *(const f32x4*)f;
    f32x4 b = *(const f32x4*)(f + 4);
    bf16x8 r;
    r[0] = (bf16_t)a[0]; r[1] = (bf16_t)a[1]; r[2] = (bf16_t)a[2]; r[3] = (bf16_t)a[3];
    r[4] = (bf16_t)b[0]; r[5] = (bf16_t)b[1]; r[6] = (bf16_t)b[2]; r[7] = (bf16_t)b[3];
    return r;
  }
}

// ---------------- probe: are inputs bf16 (1) or f32 (0)? ----------------
__global__ void k_probe(const uint32_t* __restrict__ X, int* __restrict__ flag) {
  __shared__ int cnt;
  if (threadIdx.x == 0) cnt = 0;
  __syncthreads();
  const uint32_t w = X[threadIdx.x];
  const int e = (int)((w >> 7) & 0xFF);  // exponent of low-16 as bf16
  const int sane = (e >= 110 && e <= 131) ? 1 : 0;
  atomicAdd(&cnt, sane);
  __syncthreads();
  if (threadIdx.x == 0) *flag = (cnt >= 128) ? 1 : 0;
}

// ---------------- zero fp32 accumulators ----------------
__global__ void k_zero(float* __restrict__ p, int n) {
  int i = blockIdx.x * 256 + threadIdx.x;
  if (i < n) p[i] = 0.f;
}

// ---------------- cvt: X,Wqkv (f32 or bf16) -> bf16 workspace ----------------
__global__ void k_cvt(const void* __restrict__ X, const void* __restrict__ Wqkv,
                      bf16_t* __restrict__ Xb, bf16_t* __restrict__ Wb,
                      const int* __restrict__ flagp) {
  const int isb = *flagp;
  const int G = gridDim.x * 256;
  for (int c = blockIdx.x * 256 + threadIdx.x; c < TCHUNKS; c += G) {
    const bool isX = c < XCHUNKS;
    const int lc = isX ? c : c - XCHUNKS;          // chunk within its buffer
    const void* src = isX ? X : Wqkv;
    bf16_t* dst = (isX ? Xb : Wb) + (size_t)lc * 8;
    if (isb) {
      *(bf16x8*)dst = *((const bf16x8*)src + lc);
    } else {
      const f32x4 a = *((const f32x4*)src + lc * 2);
      const f32x4 b = *((const f32x4*)src + lc * 2 + 1);
      bf16x8 r;
      r[0] = (bf16_t)a[0]; r[1] = (bf16_t)a[1]; r[2] = (bf16_t)a[2]; r[3] = (bf16_t)a[3];
      r[4] = (bf16_t)b[0]; r[5] = (bf16_t)b[1]; r[6] = (bf16_t)b[2]; r[7] = (bf16_t)b[3];
      *(bf16x8*)dst = r;
    }
  }
}

// ---------------- K1: qkv = x @ w_qkv^T ----------------
// Grid (512). jt=0..8 INSIDE the block; 2 blocks/CU; staging via
// global_load_lds (GL=true, main path) or reg-staging (fallback paths).
// q/k tiles (which<2): swapped MFMA (D row = token) -> bf16x4 stores along N.
// v tiles: original order (D row = channel) -> bf16x4 stores along C.
template <bool BF16, bool GL>
__device__ __forceinline__ void qkv_body(const void* __restrict__ X,
                                         const void* __restrict__ Wqkv,
                                         bf16_t* __restrict__ qkv,
                                         bf16_t* As, bf16_t* Bs) {
  const int tid = threadIdx.x;
  const int lane = tid & 63;
  const int wr = tid >> 7, wc = (tid >> 6) & 1;
  const int q4 = lane >> 4, l16 = lane & 15;
  const int rowB0 = blockIdx.x * 128;
  const int r0 = tid >> 2, kk = (tid & 3) << 3;
  const int bb = rowB0 >> 13;       // batch index (tiles never cross b)
  const int nB = rowB0 & 8191;      // token base within batch

  const bf16_t* XB = (const bf16_t*)X;
  const bf16_t* WB = (const bf16_t*)Wqkv;

  for (int jt = 0; jt < 9; jt++) {
    const int rowA0 = jt * 128;
    const int which = jt / 3;       // 0=q 1=k 2=v (uniform per jt)
    const int jtt = jt - which * 3;
    f32x4 acc[4][4];
#pragma unroll
    for (int i = 0; i < 4; i++)
#pragma unroll
      for (int j = 0; j < 4; j++) acc[i][j] = (f32x4){0.f, 0.f, 0.f, 0.f};

    for (int k0 = 0; k0 < CDIM; k0 += 32) {
      if constexpr (GL) {
        __syncthreads();  // prior iteration's LDS frag reads complete
        gload16(As + tid * 8,         WB + (rowA0 + r0) * CDIM + k0 + kk);
        gload16(As + (tid + 256) * 8, WB + (rowA0 + r0 + 64) * CDIM + k0 + kk);
        gload16(Bs + tid * 8,         XB + (rowB0 + r0) * CDIM + k0 + kk);
        gload16(Bs + (tid + 256) * 8, XB + (rowB0 + r0 + 64) * CDIM + k0 + kk);
        __syncthreads();  // drains vmcnt -> staging complete
      } else {
        bf16x8 a0 = load8<BF16>(Wqkv, (rowA0 + r0) * CDIM + k0 + kk);
        bf16x8 a1 = load8<BF16>(Wqkv, (rowA0 + r0 + 64) * CDIM + k0 + kk);
        bf16x8 b0 = load8<BF16>(X, (rowB0 + r0) * CDIM + k0 + kk);
        bf16x8 b1 = load8<BF16>(X, (rowB0 + r0 + 64) * CDIM + k0 + kk);
        __syncthreads();  // prior iteration's LDS frag reads complete
        *(bf16x8*)&As[tid * 8] = a0;
        *(bf16x8*)&As[(tid + 256) * 8] = a1;
        *(bf16x8*)&Bs[tid * 8] = b0;
        *(bf16x8*)&Bs[(tid + 256) * 8] = b1;
        __syncthreads();
      }
      bf16x8 af[4], bfr[4];
#pragma unroll
      for (int i = 0; i < 4; i++) {
        af[i]  = *(const bf16x8*)&As[(wr * 64 + i * 16 + l16) * 32 + q4 * 8];
        bfr[i] = *(const bf16x8*)&Bs[(wc * 64 + i * 16 + l16) * 32 + q4 * 8];
      }
      if (which < 2) {
#pragma unroll
        for (int i = 0; i < 4; i++)
#pragma unroll
          for (int j = 0; j < 4; j++) acc[i][j] = mfma16(bfr[j], af[i], acc[i][j]);
      } else {
#pragma unroll
        for (int i = 0; i < 4; i++)
#pragma unroll
          for (int j = 0; j < 4; j++) acc[i][j] = mfma16(af[i], bfr[j], acc[i][j]);
      }
    }

    if (which < 2) {
      // swapped: acc[i][j][r] = D[token = rowB0+wc*64+j*16+q4*4+r][ch = rowA0+wr*64+i*16+l16]
#pragma unroll
      for (int i = 0; i < 4; i++) {
        const int rin = jtt * 128 + wr * 64 + i * 16 + l16;  // channel within plane
        const int h = rin / 48, dh = rin - h * 48;
        bf16_t* rowp = qkv + which * WH + (bb * 8 + h) * DHN + dh * NTOK
                       + nB + wc * 64 + q4 * 4;
#pragma unroll
        for (int j = 0; j < 4; j++) {
          bf16x4 o = {(bf16_t)acc[i][j][0], (bf16_t)acc[i][j][1],
                      (bf16_t)acc[i][j][2], (bf16_t)acc[i][j][3]};
          *(bf16x4*)(rowp + j * 16) = o;
        }
      }
    } else {
      // original: acc[i][j][r] = D[ch = rowA0+wr*64+i*16+q4*4+r][token = rowB0+wc*64+j*16+l16]
#pragma unroll
      for (int i = 0; i < 4; i++) {
        const int rin0 = jtt * 128 + wr * 64 + i * 16 + q4 * 4;  // c within v
#pragma unroll
        for (int j = 0; j < 4; j++) {
          const int mg = rowB0 + wc * 64 + j * 16 + l16;
          bf16x4 o = {(bf16_t)acc[i][j][0], (bf16_t)acc[i][j][1],
                      (bf16_t)acc[i][j][2], (bf16_t)acc[i][j][3]};
          *(bf16x4*)(qkv + 2 * WH + mg * CDIM + rin0) = o;
        }
      }
    }
  }
}

// main path: inputs already bf16 in workspace; global_load_lds staging.
__global__ __launch_bounds__(256, 2) void k_gemm_qkv(
    const bf16_t* __restrict__ Xb, const bf16_t* __restrict__ Wb,
    bf16_t* __restrict__ qkv) {
  __shared__ __align__(16) bf16_t As[128 * 32];
  __shared__ __align__(16) bf16_t Bs[128 * 32];
  qkv_body<true, true>(Xb, Wb, qkv, As, Bs);
}

// fallback path (ws too small for cvt buffers): flag-gated pair, reg-staging.
__global__ __launch_bounds__(256, 2) void k_gemm_qkv_bf16(
    const void* __restrict__ X, const void* __restrict__ Wqkv,
    bf16_t* __restrict__ qkv, const int* __restrict__ flagp) {
  __shared__ __align__(16) bf16_t As[128 * 32];
  __shared__ __align__(16) bf16_t Bs[128 * 32];
  if (!*flagp) return;
  qkv_body<true, false>(X, Wqkv, qkv, As, Bs);
}

__global__ __launch_bounds__(256, 2) void k_gemm_qkv_f32(
    const void* __restrict__ X, const void* __restrict__ Wqkv,
    bf16_t* __restrict__ qkv, const int* __restrict__ flagp) {
  __shared__ __align__(16) bf16_t As[128 * 32];
  __shared__ __align__(16) bf16_t Bs[128 * 32];
  if (*flagp) return;
  qkv_body<false, false>(X, Wqkv, qkv, As, Bs);
}

// ---------------- K2: Gram S=Q K^T + sumsq ----------------
__global__ __launch_bounds__(256, 2) void k_gram(
    const bf16_t* __restrict__ qkv, float* __restrict__ S_acc, float* __restrict__ ssq_acc) {
  __shared__ __align__(16) float sm[9312];  // 37,248 B
  bf16_t* Qs = (bf16_t*)sm;                 // 6144 bf16 = [4][48][32]
  bf16_t* Ks = Qs + 6144;
  float* ssq_sm = sm + 9216;                // 96 floats

  const int tid = threadIdx.x;
  const int wave = tid >> 6, lane = tid & 63, q4 = lane >> 4, l16 = lane & 15;
  const int s = blockIdx.x, bh = blockIdx.y;
  const bf16_t* Qg = qkv + bh * DHN;
  const bf16_t* Kg = qkv + WH + bh * DHN;

  if (tid < 96) ssq_sm[tid] = 0.f;

  f32x4 acc[3][3];
#pragma unroll
  for (int i = 0; i < 3; i++)
#pragma unroll
    for (int j = 0; j < 3; j++) acc[i][j] = (f32x4){0.f, 0.f, 0.f, 0.f};
  float qss[3] = {0.f, 0.f, 0.f}, kss[3] = {0.f, 0.f, 0.f};

  for (int t0 = 0; t0 < 8; t0++) {
    const int n0 = s * 1024 + t0 * 128;
    bf16x8 qv[3], kv[3];
#pragma unroll
    for (int jj = 0; jj < 3; jj++) {
      const int c = jj * 256 + tid;
      const int st = c / 192, rem = c - st * 192;
      const int row = rem >> 2, kk = (rem & 3) << 3;
      const int gofs = row * NTOK + n0 + st * 32 + kk;
      qv[jj] = *(const bf16x8*)(Qg + gofs);
      kv[jj] = *(const bf16x8*)(Kg + gofs);
    }
    __syncthreads();
#pragma unroll
    for (int jj = 0; jj < 3; jj++) {
      *(bf16x8*)&Qs[(jj * 256 + tid) * 8] = qv[jj];
      *(bf16x8*)&Ks[(jj * 256 + tid) * 8] = kv[jj];
    }
    __syncthreads();
    bf16x8 qf[3], kf[3];
#pragma unroll
    for (int i = 0; i < 3; i++) {
      qf[i] = *(const bf16x8*)&Qs[wave * 1536 + (i * 16 + l16) * 32 + q4 * 8];
      kf[i] = *(const bf16x8*)&Ks[wave * 1536 + (i * 16 + l16) * 32 + q4 * 8];
    }
#pragma unroll
    for (int i = 0; i < 3; i++) {
#pragma unroll
      for (int u = 0; u < 8; u++) {
        const float qv2 = (float)qf[i][u], kv2 = (float)kf[i][u];
        qss[i] += qv2 * qv2;
        kss[i] += kv2 * kv2;
      }
#pragma unroll
      for (int j = 0; j < 3; j++) acc[i][j] = mfma16(qf[i], kf[j], acc[i][j]);
    }
  }

  __syncthreads();
  float* red = sm;  // 4 waves x 2304 fp32
#pragma unroll
  for (int i = 0; i < 3; i++)
#pragma unroll
    for (int j = 0; j < 3; j++)
#pragma unroll
      for (int r = 0; r < 4; r++)
        red[wave * 2304 + (i * 3 + j) * 256 + lane * 4 + r] = acc[i][j][r];
#pragma unroll
  for (int i = 0; i < 3; i++) {
    atomicAdd(&ssq_sm[i * 16 + l16], qss[i]);
    atomicAdd(&ssq_sm[48 + i * 16 + l16], kss[i]);
  }
  __syncthreads();
  for (int idx = tid; idx < 2304; idx += 256) {
    const float v = red[idx] + red[2304 + idx] + red[4608 + idx] + red[6912 + idx];
    const int tile = idx >> 8, ln = (idx >> 2) & 63, r = idx & 3;
    const int i = tile / 3, j = tile - i * 3;
    const int d = i * 16 + ((ln >> 4) << 2) + r;
    const int e = j * 16 + (ln & 15);
    atomicAdd(&S_acc[bh * 2304 + d * 48 + e], v);
  }
  if (tid < 96) atomicAdd(&ssq_acc[bh * 96 + tid], ssq_sm[tid]);
}

// ---------------- K3: softmax(S / (|q_d||k_e|)) ----------------
__global__ void k_softmax(const float* __restrict__ S_acc, const float* __restrict__ ssq_acc,
                          float* __restrict__ attn_f) {
  __shared__ float invk_sm[48];
  const int bh = blockIdx.x, d = threadIdx.x;
  if (d < 48) invk_sm[d] = 1.f / fmaxf(sqrtf(ssq_acc[bh * 96 + 48 + d]), 1e-12f);
  __syncthreads();
  if (d < 48) {
    const float invq = 1.f / fmaxf(sqrtf(ssq_acc[bh * 96 + d]), 1e-12f);
    float lg[48], mx = -1e30f;
#pragma unroll
    for (int e = 0; e < 48; e++) {
      lg[e] = S_acc[bh * 2304 + d * 48 + e] * invq * invk_sm[e];
      mx = fmaxf(mx, lg[e]);
    }
    float ssum = 0.f;
#pragma unroll
    for (int e = 0; e < 48; e++) { lg[e] = expf(lg[e] - mx); ssum += lg[e]; }
    const float inv = 1.f / ssum;
#pragma unroll
    for (int e = 0; e < 48; e++) attn_f[bh * 2304 + d * 48 + e] = lg[e] * inv;
  }
}

// ---------------- K4: Weff_b[c'][h*48+e] = sum_d Wp[c'][h*48+d] attn[bh][d][e] ------
// Register-tiny LDS-tile formulation (R10, 162us -> ~10us).
__global__ void k_weff(
    const float* __restrict__ attn_f, const void* __restrict__ Wp,
    bf16_t* __restrict__ Weff, const int* __restrict__ flagp) {
  __shared__ float a_sm[2304];  // attn[d][e]
  __shared__ float w_sm[2304];  // Wp[c'_local][d]
  const int isb = *flagp;
  const int bid = blockIdx.x;
  const int ct = bid & 7, h = (bid >> 3) & 7, b = bid >> 6;
  const int bh = b * 8 + h;
  const int tid = threadIdx.x;

  for (int i = tid; i < 2304; i += 256) {
    a_sm[i] = attn_f[bh * 2304 + i];
    const int r = i / 48, c = i - r * 48;
    const int gi = (ct * 48 + r) * CDIM + h * 48 + c;
    w_sm[i] = isb ? (float)((const bf16_t*)Wp)[gi] : ((const float*)Wp)[gi];
  }
  __syncthreads();

  for (int o = tid; o < 2304; o += 256) {
    const int r = o / 48, e = o - r * 48;
    float s = 0.f;
#pragma unroll 8
    for (int d = 0; d < 48; d++) s += w_sm[r * 48 + d] * a_sm[d * 48 + e];
    Weff[b * 147456 + (ct * 48 + r) * CDIM + h * 48 + e] = (bf16_t)s;
  }
}

// ---------------- K5: out[b,n,c'] = sum_c Weff_b[c'][c] V[b,n,c] + bias[c'] --------
// Grid (64 nt, 8 b); ct=0..2 INSIDE; 2 blocks/CU; global_load_lds staging.
__global__ __launch_bounds__(256, 2) void k_gemm_out(
    const bf16_t* __restrict__ Weff, const bf16_t* __restrict__ qkv,
    const void* __restrict__ bias, void* __restrict__ out, const int* __restrict__ flagp) {
  __shared__ __align__(16) bf16_t As[128 * 32];
  __shared__ __align__(16) bf16_t Bs[128 * 32];
  const int isb = *flagp;
  const int tid = threadIdx.x;
  const int lane = tid & 63;
  const int wr = tid >> 7, wc = (tid >> 6) & 1;
  const int q4 = lane >> 4, l16 = lane & 15;
  const int b = blockIdx.y;
  const int rowB0 = blockIdx.x * 128;  // n tile
  const bf16_t* Aa = Weff + b * 147456;
  const bf16_t* Ba = qkv + 2 * WH + b * (NTOK * CDIM);
  const int r0 = tid >> 2, kk = (tid & 3) << 3;

  for (int ct = 0; ct < 3; ct++) {
    const int rowA0 = ct * 128;
    f32x4 acc[4][4];
#pragma unroll
    for (int i = 0; i < 4; i++)
#pragma unroll
      for (int j = 0; j < 4; j++) acc[i][j] = (f32x4){0.f, 0.f, 0.f, 0.f};

    for (int k0 = 0; k0 < CDIM; k0 += 32) {
      __syncthreads();  // prior iteration's LDS frag reads complete
      gload16(As + tid * 8,         Aa + (rowA0 + r0) * CDIM + k0 + kk);
      gload16(As + (tid + 256) * 8, Aa + (rowA0 + r0 + 64) * CDIM + k0 + kk);
      gload16(Bs + tid * 8,         Ba + (rowB0 + r0) * CDIM + k0 + kk);
      gload16(Bs + (tid + 256) * 8, Ba + (rowB0 + r0 + 64) * CDIM + k0 + kk);
      __syncthreads();  // drains vmcnt -> staging complete
      bf16x8 af[4], bfr[4];
#pragma unroll
      for (int i = 0; i < 4; i++) {
        af[i]  = *(const bf16x8*)&As[(wr * 64 + i * 16 + l16) * 32 + q4 * 8];
        bfr[i] = *(const bf16x8*)&Bs[(wc * 64 + i * 16 + l16) * 32 + q4 * 8];
      }
#pragma unroll
      for (int i = 0; i < 4; i++)
#pragma unroll
        for (int j = 0; j < 4; j++) acc[i][j] = mfma16(af[i], bfr[j], acc[i][j]);
    }

#pragma unroll
    for (int i = 0; i < 4; i++) {
      const int cg = rowA0 + wr * 64 + i * 16 + q4 * 4;
      float bv[4];
#pragma unroll
      for (int r = 0; r < 4; r++)
        bv[r] = isb ? (float)((const bf16_t*)bias)[cg + r] : ((const float*)bias)[cg + r];
#pragma unroll
      for (int j = 0; j < 4; j++) {
        const int ng = rowB0 + wc * 64 + j * 16 + l16;
        const int oi = (b * NTOK + ng) * CDIM + cg;
        if (isb) {
          bf16x4 o = {(bf16_t)(acc[i][j][0] + bv[0]), (bf16_t)(acc[i][j][1] + bv[1]),
                      (bf16_t)(acc[i][j][2] + bv[2]), (bf16_t)(acc[i][j][3] + bv[3])};
          *(bf16x4*)((bf16_t*)out + oi) = o;
        } else {
          f32x4 o = {acc[i][j][0] + bv[0], acc[i][j][1] + bv[1],
                     acc[i][j][2] + bv[2], acc[i][j][3] + bv[3]};
          *(f32x4*)((float*)out + oi) = o;
        }
      }
    }
  }
}

extern "C" void kernel_launch(void* const* d_in, const int* in_sizes, int n_in,
                              void* d_out, int out_size, void* d_ws, size_t ws_size,
                              hipStream_t stream) {
  (void)in_sizes; (void)n_in; (void)out_size;
  const void* X    = d_in[0];
  const void* Wqkv = d_in[1];
  const void* Wp   = d_in[2];
  const void* bias = d_in[3];

  char* ws = (char*)d_ws;
  bf16_t* qkv    = (bf16_t*)ws;                     // 3*WH bf16 = 150,994,944 B
  float*  S_acc  = (float*)(ws + 150994944);        // 64*2304 f32
  float*  ssq    = (float*)(ws + 151584768);        // 64*96 f32
  float*  attn_f = (float*)(ws + 151609344);        // 64*2304 f32
  bf16_t* Weff   = (bf16_t*)(ws + 152199168);       // 8*384*384 bf16
  int*    flag   = (int*)(ws + 154558464);
  bf16_t* Xb     = (bf16_t*)(ws + 154558720);       // 50,331,648 B
  bf16_t* Wb     = (bf16_t*)(ws + 204890368);       // 884,736 B -> end 205,775,104

  const bool have_cvt_ws = ws_size >= 205775104ULL;

  k_probe<<<dim3(1), 256, 0, stream>>>((const uint32_t*)X, flag);
  k_zero<<<dim3(600), 256, 0, stream>>>(S_acc, 153600);
  if (have_cvt_ws) {
    k_cvt<<<dim3(2048), 256, 0, stream>>>(X, Wqkv, Xb, Wb, flag);
    k_gemm_qkv<<<dim3(512), 256, 0, stream>>>(Xb, Wb, qkv);
  } else {
    k_gemm_qkv_bf16<<<dim3(512), 256, 0, stream>>>(X, Wqkv, qkv, flag);
    k_gemm_qkv_f32<<<dim3(512), 256, 0, stream>>>(X, Wqkv, qkv, flag);
  }
  k_gram<<<dim3(8, 64), 256, 0, stream>>>(qkv, S_acc, ssq);
  k_softmax<<<dim3(64), 64, 0, stream>>>(S_acc, ssq, attn_f);
  k_weff<<<dim3(512), 256, 0, stream>>>(attn_f, Wp, Weff, flag);
  k_gemm_out<<<dim3(64, 8), 256, 0, stream>>>(Weff, qkv, bias, d_out, flag);
}